// Round 3
// baseline (9056.932 us; speedup 1.0000x reference)
//
#include <hip/hip_runtime.h>
#include <hip/hip_bf16.h>
#include <cstdint>

typedef __bf16 bf16;
typedef __bf16 bf16x8 __attribute__((ext_vector_type(8)));
typedef float  f32x4  __attribute__((ext_vector_type(4)));
typedef uint32_t u32x4 __attribute__((ext_vector_type(4)));

#define D_DIM   1024
#define ND      3072
#define B_SZ    32
#define U_SZ    512
#define T_SZ    513
#define M_REAL  (B_SZ * T_SZ)   // 16416
#define WXS_LD  1032            // padded k-stride (bf16 elems)
#define A_LD    1032
#define XP_LD   20              // xpx row stride (floats), 16B-aligned rows

#define AGENT __HIP_MEMORY_SCOPE_AGENT
#define WG    __HIP_MEMORY_SCOPE_WORKGROUP

__device__ __forceinline__ f32x4 mfma16(bf16x8 a, bf16x8 b, f32x4 c) {
    return __builtin_amdgcn_mfma_f32_16x16x32_bf16(a, b, c, 0, 0, 0);
}

struct bfpair { bf16x8 hi, lo; };

// split 8 consecutive fp32 into bf16 hi + bf16 residual lo
__device__ __forceinline__ bfpair split8(const float* p) {
    f32x4 a = *(const f32x4*)p;
    f32x4 b = *(const f32x4*)(p + 4);
    bfpair r;
#pragma unroll
    for (int j = 0; j < 4; ++j) {
        r.hi[j] = (bf16)a[j];
        r.lo[j] = (bf16)(a[j] - (float)r.hi[j]);
        r.hi[4 + j] = (bf16)b[j];
        r.lo[4 + j] = (bf16)(b[j] - (float)r.hi[4 + j]);
    }
    return r;
}

// convert 8 consecutive fp32 to bf16
__device__ __forceinline__ bf16x8 cvt8(const float* p) {
    f32x4 a = *(const f32x4*)p;
    f32x4 b = *(const f32x4*)(p + 4);
    bf16x8 r;
#pragma unroll
    for (int j = 0; j < 4; ++j) { r[j] = (bf16)a[j]; r[4 + j] = (bf16)b[j]; }
    return r;
}

// unpack 8 packed uint32 (hi bf16 | lo bf16 << 16) -> hi8, lo8 via v_perm
__device__ __forceinline__ bfpair unpack8(const uint32_t* p) {
    u32x4 a = *(const u32x4*)p;
    u32x4 b = *(const u32x4*)(p + 4);
    union { uint32_t u[4]; bf16x8 v; } H, L;
    H.u[0] = __builtin_amdgcn_perm(a.y, a.x, 0x05040100u);
    H.u[1] = __builtin_amdgcn_perm(a.w, a.z, 0x05040100u);
    H.u[2] = __builtin_amdgcn_perm(b.y, b.x, 0x05040100u);
    H.u[3] = __builtin_amdgcn_perm(b.w, b.z, 0x05040100u);
    L.u[0] = __builtin_amdgcn_perm(a.y, a.x, 0x07060302u);
    L.u[1] = __builtin_amdgcn_perm(a.w, a.z, 0x07060302u);
    L.u[2] = __builtin_amdgcn_perm(b.y, b.x, 0x07060302u);
    L.u[3] = __builtin_amdgcn_perm(b.w, b.z, 0x07060302u);
    bfpair r; r.hi = H.v; r.lo = L.v;
    return r;
}

// ---------------------------------------------------------------------------
// Transpose fp32 Wd [K][N] -> bf16 hi/lo planes WdT[N][K]
// ---------------------------------------------------------------------------
__global__ void transpose_split(const float* __restrict__ in,
                                bf16* __restrict__ out_hi, bf16* __restrict__ out_lo,
                                int R, int C) {
    __shared__ float tile[32][33];
    const int c0 = blockIdx.x * 32, r0 = blockIdx.y * 32;
    const int tx = threadIdx.x, ty = threadIdx.y;   // 32 x 8
    for (int i = 0; i < 32; i += 8)
        tile[ty + i][tx] = in[(size_t)(r0 + ty + i) * C + c0 + tx];
    __syncthreads();
    for (int i = 0; i < 32; i += 8) {
        const float v  = tile[tx][ty + i];
        const bf16  hi = (bf16)v;
        out_hi[(size_t)(c0 + ty + i) * R + r0 + tx] = hi;
        out_lo[(size_t)(c0 + ty + i) * R + r0 + tx] = (bf16)(v - (float)hi);
    }
}

// ---------------------------------------------------------------------------
// GRU scan (R9): R8 compute structure + low-traffic one-hop barrier.
//   64 blocks x 384 threads; block = one 16-col n-slice, all 32 batches.
//   Waves 0-3: gate waves (k-split, 192 AGPR-resident Wh-hi fragments each;
//     finishers = khalf==0 combine partials in-register and publish 2x u64
//     exchanges). Waves 4,5: xp(t+1) producers (double-buffered xpx).
//   Barrier (R9): ONLY wave 4 polls the 64 global slots (64 lanes, one slot
//     each, own block special-cased) -> 4K loads/iter device-wide instead of
//     R8's 16K (the R8 poll storm saturated the MALL and inflated every
//     critical-path latency; also caused a 27.8 ms outlier dispatch).
//     Gate waves spin on a per-block LDS go flag (zero global traffic).
//     Arrival store by wave 4 lane 0 after sync #2 (same drain ordering).
// ---------------------------------------------------------------------------
__global__ __launch_bounds__(384, 1)
void gru_scan(const float* __restrict__ Wx,    const float* __restrict__ Wh,
              const float* __restrict__ bx,    const float* __restrict__ bh,
              const float* __restrict__ h0,    const float* __restrict__ embed,
              const int* __restrict__ y,       uint32_t* __restrict__ ghs,
              int* __restrict__ flags)
{
    __shared__ __align__(16) bf16 WxS[48 * WXS_LD];       // [c = gate*16+cl][k]
    __shared__ __align__(16) float xpx[2][96 * XP_LD];    // [g*32+batch][n-sub]
    __shared__ __align__(16) float pP[2][3][16][20];      // [grp][gate][batch][n-sub]
    __shared__ __align__(16) float bxs[3][16], bhs[3][16];
    __shared__ int go_lds;

    const int tid  = threadIdx.x;
    const int wave = tid >> 6, lane = tid & 63;
    const int quad = lane >> 4, l15 = lane & 15;
    const int n0 = blockIdx.x * 16;
    int* slots = flags;          // slot for block b at flags[b*16]  (64-B stride)

    if (tid == 0) go_lds = 0;

    // ---- one-time: gather Wx slice [48 cols][1024 k] from fp32 Wx[k][3D] ----
    for (int idx = tid; idx < 3 * 1024 * 16; idx += 384) {
        const int cl = idx & 15;
        const int k  = (idx >> 4) & 1023;
        const int g  = idx >> 14;            // 0..2
        WxS[(g * 16 + cl) * WXS_LD + k] = (bf16)Wx[(size_t)k * ND + g * D_DIM + n0 + cl];
    }
    if (tid < 48) {
        bxs[tid >> 4][tid & 15] = bx[(tid >> 4) * D_DIM + n0 + (tid & 15)];
        bhs[tid >> 4][tid & 15] = bh[(tid >> 4) * D_DIM + n0 + (tid & 15)];
    }

    const int khalf = wave & 1;              // gate waves: k-half
    const int grp   = (wave >> 1) & 1;       // gate waves: batch group
    const int batch = (wave < 4) ? grp * 16 + l15 : (wave & 1) * 16 + l15;

    // ---- one-time: Wh half-slice for ALL 3 gates into gate-wave registers ----
    // A-fragment: lane supplies Wh[k = khalf*512 + kk*32 + quad*8 + j][n0+l15]
    bf16x8 bregZ[16], bregR[16], bregH[16];
    if (wave < 4) {
#pragma unroll
        for (int kk = 0; kk < 16; ++kk) {
            bf16x8 vz, vr, vh;
#pragma unroll
            for (int j = 0; j < 8; ++j) {
                const size_t krow =
                    (size_t)(khalf * 512 + kk * 32 + quad * 8 + j) * ND + n0 + l15;
                vz[j] = (bf16)Wh[krow];
                vr[j] = (bf16)Wh[krow + D_DIM];
                vh[j] = (bf16)Wh[krow + 2 * D_DIM];
            }
            bregZ[kk] = vz; bregR[kk] = vr; bregH[kk] = vh;
        }
    }

    f32x4 holdv = *(const f32x4*)(h0 + n0 + quad * 4);   // h0 broadcast over batch
    unsigned long long junk = 0;

    __syncthreads();   // WxS / biases / go_lds ready

    // ---- pre-loop: xp(0), all tokens NULL (embed row 0) -> xpx[0] ----
    if (wave >= 4) {
        const float* xrow = embed + quad * 8;
        f32x4 ax0 = {}, ax1 = {}, ax2 = {};
#pragma unroll
        for (int ks = 0; ks < 32; ++ks) {
            bf16x8 xa = cvt8(xrow + ks * 32);
            bf16x8 w0 = *(const bf16x8*)(WxS + (l15)      * WXS_LD + ks * 32 + quad * 8);
            bf16x8 w1 = *(const bf16x8*)(WxS + (16 + l15) * WXS_LD + ks * 32 + quad * 8);
            bf16x8 w2 = *(const bf16x8*)(WxS + (32 + l15) * WXS_LD + ks * 32 + quad * 8);
            ax0 = mfma16(w0, xa, ax0);   // rows = n-sub, cols = batch
            ax1 = mfma16(w1, xa, ax1);
            ax2 = mfma16(w2, xa, ax2);
        }
        *(f32x4*)(xpx[0] + (batch)      * XP_LD + quad * 4) = ax0;
        *(f32x4*)(xpx[0] + (32 + batch) * XP_LD + quad * 4) = ax1;
        *(f32x4*)(xpx[0] + (64 + batch) * XP_LD + quad * 4) = ax2;
    }
    __syncthreads();   // xpx[0] ready

    for (int t = 0; t < T_SZ; ++t) {
        f32x4 sz = {}, sr = {}, sh = {};    // this wave's k-half partials

        if (wave < 4) {
            // ---- hp half: 6 chains (3 gates x hi/lo h), 16-deep ----
            f32x4 azh = {}, azl = {}, arh = {}, arl = {}, ahh = {}, ahl = {};
            if (t == 0) {
                const float* hrow = h0 + khalf * 512 + quad * 8;
#pragma unroll
                for (int kk = 0; kk < 16; ++kk) {
                    bfpair h8 = split8(hrow + kk * 32);
                    azh = mfma16(bregZ[kk], h8.hi, azh);
                    azl = mfma16(bregZ[kk], h8.lo, azl);
                    arh = mfma16(bregR[kk], h8.hi, arh);
                    arl = mfma16(bregR[kk], h8.lo, arl);
                    ahh = mfma16(bregH[kk], h8.hi, ahh);
                    ahl = mfma16(bregH[kk], h8.lo, ahl);
                }
            } else {
                const uint32_t* hrow = ghs
                    + ((size_t)batch * T_SZ + (t - 1)) * D_DIM + khalf * 512 + quad * 8;
#pragma unroll
                for (int kk = 0; kk < 16; ++kk) {
                    bfpair h8 = unpack8(hrow + kk * 32);
                    azh = mfma16(bregZ[kk], h8.hi, azh);
                    azl = mfma16(bregZ[kk], h8.lo, azl);
                    arh = mfma16(bregR[kk], h8.hi, arh);
                    arl = mfma16(bregR[kk], h8.lo, arl);
                    ahh = mfma16(bregH[kk], h8.hi, ahh);
                    ahl = mfma16(bregH[kk], h8.lo, ahl);
                }
            }
            sz = azh + azl; sr = arh + arl; sh = ahh + ahl;
            if (khalf) {   // partner half -> LDS (stride-20 rows: conflict-free)
                *(f32x4*)&pP[grp][0][l15][quad * 4] = sz;
                *(f32x4*)&pP[grp][1][l15][quad * 4] = sr;
                *(f32x4*)&pP[grp][2][l15][quad * 4] = sh;
            }
        } else if (t < U_SZ) {
            // ---- xp(t+1), off critical path ----
            const int tok = y[batch * U_SZ + t] & 1023;   // token at step t+1
            const float* xrow = embed + (size_t)tok * D_DIM + quad * 8;
            const int p = (t + 1) & 1;
            f32x4 ax0 = {}, ax1 = {}, ax2 = {};
#pragma unroll
            for (int ks = 0; ks < 32; ++ks) {
                bf16x8 xa = cvt8(xrow + ks * 32);
                bf16x8 w0 = *(const bf16x8*)(WxS + (l15)      * WXS_LD + ks * 32 + quad * 8);
                bf16x8 w1 = *(const bf16x8*)(WxS + (16 + l15) * WXS_LD + ks * 32 + quad * 8);
                bf16x8 w2 = *(const bf16x8*)(WxS + (32 + l15) * WXS_LD + ks * 32 + quad * 8);
                ax0 = mfma16(w0, xa, ax0);
                ax1 = mfma16(w1, xa, ax1);
                ax2 = mfma16(w2, xa, ax2);
            }
            *(f32x4*)(xpx[p] + (batch)      * XP_LD + quad * 4) = ax0;
            *(f32x4*)(xpx[p] + (32 + batch) * XP_LD + quad * 4) = ax1;
            *(f32x4*)(xpx[p] + (64 + batch) * XP_LD + quad * 4) = ax2;
        }

        __syncthreads();   // #1: partials + xpx[t&1] visible

        if (wave < 4 && khalf == 0) {
            // ---- finisher: add partner half, gates in-register, publish ----
            const int p = t & 1;
            const f32x4 qz = *(const f32x4*)&pP[grp][0][l15][quad * 4];
            const f32x4 qr = *(const f32x4*)&pP[grp][1][l15][quad * 4];
            const f32x4 qh = *(const f32x4*)&pP[grp][2][l15][quad * 4];
            const f32x4 xz = *(const f32x4*)(xpx[p] + (batch)      * XP_LD + quad * 4);
            const f32x4 xr = *(const f32x4*)(xpx[p] + (32 + batch) * XP_LD + quad * 4);
            const f32x4 xh = *(const f32x4*)(xpx[p] + (64 + batch) * XP_LD + quad * 4);
            const f32x4 bxz = *(const f32x4*)(&bxs[0][quad * 4]);
            const f32x4 bxr = *(const f32x4*)(&bxs[1][quad * 4]);
            const f32x4 bxh = *(const f32x4*)(&bxs[2][quad * 4]);
            const f32x4 bhz = *(const f32x4*)(&bhs[0][quad * 4]);
            const f32x4 bhr = *(const f32x4*)(&bhs[1][quad * 4]);
            const f32x4 bhh = *(const f32x4*)(&bhs[2][quad * 4]);
            uint32_t pk[4];
#pragma unroll
            for (int i = 0; i < 4; ++i) {
                const float hz  = sz[i] + qz[i] + bhz[i];
                const float hr  = sr[i] + qr[i] + bhr[i];
                const float hhv = sh[i] + qh[i] + bhh[i];
                const float z  = 1.f / (1.f + __expf(-(xz[i] + bxz[i] + hz)));
                const float r  = 1.f / (1.f + __expf(-(xr[i] + bxr[i] + hr)));
                const float pa = xh[i] + bxh[i] + r * hhv;
                const float hc = 1.f - 2.f / (__expf(2.f * pa) + 1.f);   // tanh(pa)
                const float hn = z * holdv[i] + (1.f - z) * hc;
                holdv[i] = hn;
                const bf16 hi = (bf16)hn;
                const bf16 lo = (bf16)(hn - (float)hi);
                pk[i] = (uint32_t)__builtin_bit_cast(uint16_t, hi)
                      | ((uint32_t)__builtin_bit_cast(uint16_t, lo) << 16);
            }
            const unsigned long long e0 = (unsigned long long)pk[0]
                                        | ((unsigned long long)pk[1] << 32);
            const unsigned long long e1 = (unsigned long long)pk[2]
                                        | ((unsigned long long)pk[3] << 32);
            unsigned long long* dst = (unsigned long long*)
                (ghs + ((size_t)batch * T_SZ + t) * D_DIM + n0 + quad * 4);
            junk ^= __hip_atomic_exchange(dst,     e0, __ATOMIC_RELAXED, AGENT);
            junk ^= __hip_atomic_exchange(dst + 1, e1, __ATOMIC_RELAXED, AGENT);
        }

        __syncthreads();   // #2: drains exchanges (vmcnt0) for the whole block

        // ---- one-hop device barrier, low-traffic form ----
        if (t + 1 < T_SZ) {
            const int tv = t + 1;
            if (wave == 4) {
                if (lane == 0)
                    __hip_atomic_store(slots + (blockIdx.x << 4), tv,
                                       __ATOMIC_RELAXED, AGENT);
                int ok;
                do {
                    const int s = __hip_atomic_load(slots + (lane << 4),
                                                    __ATOMIC_RELAXED, AGENT);
                    ok = (lane == blockIdx.x) || (s >= tv);
                } while (!__all(ok));
                if (lane == 0)
                    __hip_atomic_store(&go_lds, tv, __ATOMIC_RELAXED, WG);
            } else if (wave < 4) {
                while (__hip_atomic_load(&go_lds, __ATOMIC_RELAXED, WG) < tv) {}
            }
            // wave 5 free-runs: its next xpx write targets the buffer the
            // finishers consumed before sync #2, and it touches no
            // cross-block state.
        }
    }

    // consume junk so the exchanges keep their returning form
    if (junk == 0xDEADBEEFDEADBEEFull) flags[1023] = 1;
}

// ---------------------------------------------------------------------------
// In-place row-block GEMM: rows (packed hi/lo h) -> fp32 out rows.
// ---------------------------------------------------------------------------
__global__ __launch_bounds__(256, 1)
void gemm_rows_inplace(float* __restrict__ C,
                       const bf16* __restrict__ WdTh, const bf16* __restrict__ WdTl,
                       const float* __restrict__ bd)
{
    __shared__ __align__(16) bf16 Ah[32 * A_LD];
    __shared__ __align__(16) bf16 Al[32 * A_LD];
    const int tid  = threadIdx.x;
    const int wave = tid >> 6, lane = tid & 63;
    const int quad = lane >> 4, l15 = lane & 15;
    const size_t r0 = (size_t)blockIdx.x * 32;
    const uint32_t* Cw = (const uint32_t*)C;

    for (int idx = tid; idx < 32 * 128; idx += 256) {
        const int r = idx >> 7, ch = idx & 127;
        bfpair p = unpack8(Cw + (r0 + r) * D_DIM + ch * 8);
        *(bf16x8*)(Ah + r * A_LD + ch * 8) = p.hi;
        *(bf16x8*)(Al + r * A_LD + ch * 8) = p.lo;
    }
    __syncthreads();

    f32x4 acc[2][16] = {};
    const int nbase = wave * 256;
    for (int ks = 0; ks < 32; ++ks) {
        bf16x8 a0h = *(const bf16x8*)(Ah + (l15)      * A_LD + ks * 32 + quad * 8);
        bf16x8 a0l = *(const bf16x8*)(Al + (l15)      * A_LD + ks * 32 + quad * 8);
        bf16x8 a1h = *(const bf16x8*)(Ah + (16 + l15) * A_LD + ks * 32 + quad * 8);
        bf16x8 a1l = *(const bf16x8*)(Al + (16 + l15) * A_LD + ks * 32 + quad * 8);
#pragma unroll
        for (int nt = 0; nt < 16; ++nt) {
            const size_t boff = (size_t)(nbase + nt * 16 + l15) * D_DIM + ks * 32 + quad * 8;
            bf16x8 bhv = *(const bf16x8*)(WdTh + boff);
            bf16x8 blv = *(const bf16x8*)(WdTl + boff);
            acc[0][nt] = mfma16(a0h, bhv, acc[0][nt]);
            acc[0][nt] = mfma16(a0l, bhv, acc[0][nt]);
            acc[0][nt] = mfma16(a0h, blv, acc[0][nt]);
            acc[1][nt] = mfma16(a1h, bhv, acc[1][nt]);
            acc[1][nt] = mfma16(a1l, bhv, acc[1][nt]);
            acc[1][nt] = mfma16(a1h, blv, acc[1][nt]);
        }
    }

#pragma unroll
    for (int nt = 0; nt < 16; ++nt) {
        const int col = nbase + nt * 16 + l15;
        const float bvl = bd[col];
#pragma unroll
        for (int mt = 0; mt < 2; ++mt)
#pragma unroll
            for (int i = 0; i < 4; ++i)
                C[(r0 + mt * 16 + quad * 4 + i) * D_DIM + col] =
                    acc[mt][nt][i] + bvl;
    }
}

// ---------------------------------------------------------------------------
extern "C" void kernel_launch(void* const* d_in, const int* in_sizes, int n_in,
                              void* d_out, int out_size, void* d_ws, size_t ws_size,
                              hipStream_t stream) {
    (void)in_sizes; (void)n_in; (void)out_size; (void)ws_size;
    const int*   y     = (const int*)  d_in[0];
    const float* embed = (const float*)d_in[1];
    const float* Wx    = (const float*)d_in[2];
    const float* Wh    = (const float*)d_in[3];
    const float* bx    = (const float*)d_in[4];
    const float* bh    = (const float*)d_in[5];
    const float* Wd    = (const float*)d_in[6];
    const float* bd    = (const float*)d_in[7];
    const float* h0    = (const float*)d_in[8];
    float* out = (float*)d_out;

    // workspace: WdT hi/lo (2+2 MB) + flags (8 KB)
    bf16* WdTh = (bf16*)d_ws;
    bf16* WdTl = WdTh + (size_t)D_DIM * D_DIM;
    int* flags = (int*)((char*)d_ws + (size_t)D_DIM * D_DIM * 4);

    hipMemsetAsync(flags, 0, 8192, stream);

    transpose_split<<<dim3(D_DIM / 32, D_DIM / 32), dim3(32, 8), 0, stream>>>(
        Wd, WdTh, WdTl, D_DIM, D_DIM);

    // GRU scan with fused input projections; packed h history -> d_out rows
    gru_scan<<<64, 384, 0, stream>>>(Wx, Wh, bx, bh, h0, embed, y,
                                     (uint32_t*)out, flags);

    // In-place: out rows = h rows @ Wd + bd
    gemm_rows_inplace<<<M_REAL / 32, 256, 0, stream>>>(out, WdTh, WdTl, bd);
}

// Round 4
// 7743.337 us; speedup vs baseline: 1.1696x; 1.1696x over previous
//
#include <hip/hip_runtime.h>
#include <hip/hip_bf16.h>
#include <cstdint>

typedef __bf16 bf16;
typedef __bf16 bf16x8 __attribute__((ext_vector_type(8)));
typedef float  f32x4  __attribute__((ext_vector_type(4)));
typedef uint32_t u32x4 __attribute__((ext_vector_type(4)));

#define D_DIM   1024
#define ND      3072
#define B_SZ    32
#define U_SZ    512
#define T_SZ    513
#define M_REAL  (B_SZ * T_SZ)   // 16416
#define NCHUNK  (M_REAL / 32)   // 513 row-chunks of 32
#define WXS_LD  1032            // padded k-stride
#define A_LD    1032

#define AGENT __HIP_MEMORY_SCOPE_AGENT

__device__ __forceinline__ f32x4 mfma16(bf16x8 a, bf16x8 b, f32x4 c) {
    return __builtin_amdgcn_mfma_f32_16x16x32_bf16(a, b, c, 0, 0, 0);
}

struct bfpair { bf16x8 hi, lo; };

// split 8 consecutive fp32 into bf16 hi + bf16 residual lo
__device__ __forceinline__ bfpair split8(const float* p) {
    f32x4 a = *(const f32x4*)p;
    f32x4 b = *(const f32x4*)(p + 4);
    bfpair r;
#pragma unroll
    for (int j = 0; j < 4; ++j) {
        r.hi[j] = (bf16)a[j];
        r.lo[j] = (bf16)(a[j] - (float)r.hi[j]);
        r.hi[4 + j] = (bf16)b[j];
        r.lo[4 + j] = (bf16)(b[j] - (float)r.hi[4 + j]);
    }
    return r;
}

// convert 8 consecutive fp32 to bf16
__device__ __forceinline__ bf16x8 cvt8(const float* p) {
    f32x4 a = *(const f32x4*)p;
    f32x4 b = *(const f32x4*)(p + 4);
    bf16x8 r;
#pragma unroll
    for (int j = 0; j < 4; ++j) { r[j] = (bf16)a[j]; r[4 + j] = (bf16)b[j]; }
    return r;
}

// unpack 8 packed uint32 (hi bf16 | lo bf16 << 16) -> hi8, lo8 via v_perm
__device__ __forceinline__ bfpair unpack8(const uint32_t* p) {
    u32x4 a = *(const u32x4*)p;
    u32x4 b = *(const u32x4*)(p + 4);
    union { uint32_t u[4]; bf16x8 v; } H, L;
    H.u[0] = __builtin_amdgcn_perm(a.y, a.x, 0x05040100u);
    H.u[1] = __builtin_amdgcn_perm(a.w, a.z, 0x05040100u);
    H.u[2] = __builtin_amdgcn_perm(b.y, b.x, 0x05040100u);
    H.u[3] = __builtin_amdgcn_perm(b.w, b.z, 0x05040100u);
    L.u[0] = __builtin_amdgcn_perm(a.y, a.x, 0x07060302u);
    L.u[1] = __builtin_amdgcn_perm(a.w, a.z, 0x07060302u);
    L.u[2] = __builtin_amdgcn_perm(b.y, b.x, 0x07060302u);
    L.u[3] = __builtin_amdgcn_perm(b.w, b.z, 0x07060302u);
    bfpair r; r.hi = H.v; r.lo = L.v;
    return r;
}

// ---------------------------------------------------------------------------
// Transpose fp32 Wd [K][N] -> bf16 hi/lo planes WdT[N][K]
// ---------------------------------------------------------------------------
__global__ void transpose_split(const float* __restrict__ in,
                                bf16* __restrict__ out_hi, bf16* __restrict__ out_lo,
                                int R, int C) {
    __shared__ float tile[32][33];
    const int c0 = blockIdx.x * 32, r0 = blockIdx.y * 32;
    const int tx = threadIdx.x, ty = threadIdx.y;   // 32 x 8
    for (int i = 0; i < 32; i += 8)
        tile[ty + i][tx] = in[(size_t)(r0 + ty + i) * C + c0 + tx];
    __syncthreads();
    for (int i = 0; i < 32; i += 8) {
        const float v  = tile[tx][ty + i];
        const bf16  hi = (bf16)v;
        out_hi[(size_t)(c0 + ty + i) * R + r0 + tx] = hi;
        out_lo[(size_t)(c0 + ty + i) * R + r0 + tx] = (bf16)(v - (float)hi);
    }
}

// ---------------------------------------------------------------------------
// Fused GRU scan + streamed output GEMM (R10).
//   Blocks 0..127: the proven R6 scan, byte-identical structure
//     (128 persistent WGs x 256 thr; block = (mhalf, 16-dim slice); zero-RMW
//     leader-sweep barrier). Only change: the barrier also runs after the
//     last step, publishing go=T_SZ as the "scan fully done" value.
//   Blocks 128..255: GEMM consumers. Grid-stride over the 513 row-chunks
//     (32 rows = one batch, consecutive t). Chunk is safe to read+overwrite
//     in-place once go >= min(t_max+2, T_SZ): the scan at step g only reads
//     row g-1, so rows <= g-2 are dead. Consumers poll a go line with
//     s_sleep backoff; they never touch slots.
//   LDS union (scan 109 KB / gemm 132 KB -> 132 KB) forces 1 block/CU, so
//   scan and consumer blocks never share a CU; grid 256 <= 256 CUs keeps
//   all scan blocks co-resident.
// ---------------------------------------------------------------------------
struct ScanS {
    bf16  WxS[48 * WXS_LD];     // [c = gate*16+cl][k]
    float hpx[48 * 17];
    float xpx[2][48 * 17];
    float bhs[48], bxs[48];
};
struct GemmS {
    bf16 Ah[32 * A_LD];
    bf16 Al[32 * A_LD];
};
union SMemU { ScanS s; GemmS g; };

__global__ __launch_bounds__(256, 1)
void gru_scan(const float* __restrict__ Wx,    const float* __restrict__ Wh,
              const float* __restrict__ bx,    const float* __restrict__ bh,
              const float* __restrict__ h0,    const float* __restrict__ embed,
              const int* __restrict__ y,       uint32_t* __restrict__ ghs,
              int* __restrict__ flags,
              const bf16* __restrict__ WdTh,   const bf16* __restrict__ WdTl,
              const float* __restrict__ bd)
{
    __shared__ __align__(16) SMemU su;

    const int tid  = threadIdx.x;
    const int wave = tid >> 6, lane = tid & 63;
    const int quad = lane >> 4, l15 = lane & 15;
    int* slots = flags;          // slot for block b at flags[b*4]  (16-B stride)
    int* go    = flags + 512;    // go line j at flags[512 + j*16], j=0..7

    if (blockIdx.x < 128) {
        // =================== scan path (R6 verbatim) =======================
        const int mhalf = blockIdx.x & 1;
        const int n0 = (blockIdx.x >> 1) * 16;

        // ---- one-time: gather Wx slice [48 cols][1024 k] from Wx[k][3D] ----
        for (int idx = tid; idx < 3 * 1024 * 16; idx += 256) {
            const int cl = idx & 15;
            const int k  = (idx >> 4) & 1023;
            const int g  = idx >> 14;            // 0..2
            su.s.WxS[(g * 16 + cl) * WXS_LD + k] =
                (bf16)Wx[(size_t)k * ND + g * D_DIM + n0 + cl];
        }
        if (tid < 48) {
            su.s.bhs[tid] = bh[(tid >> 4) * D_DIM + n0 + (tid & 15)];
            su.s.bxs[tid] = bx[(tid >> 4) * D_DIM + n0 + (tid & 15)];
        }

        // ---- one-time: gather Wh gate-slice into registers (waves 0..2) ----
        bf16x8 breg[32];
        if (wave < 3) {
#pragma unroll
            for (int ks = 0; ks < 32; ++ks) {
                bf16x8 v;
#pragma unroll
                for (int j = 0; j < 8; ++j)
                    v[j] = (bf16)Wh[(size_t)(ks * 32 + quad * 8 + j) * ND
                                    + wave * D_DIM + n0 + l15];
                breg[ks] = v;
            }
        }

        // gate-phase identity: one (batch, dim) output per thread
        const int gml = tid >> 4, nl = tid & 15;
        const int gb  = mhalf * 16 + gml;
        const int gn  = n0 + nl;
        float hold = h0[gn];
        uint32_t pkjunk = 0;

        __syncthreads();

        // ---- pre-loop: xp(0), all tokens NULL (embed row 0) -> xpx[0] ----
        if (wave == 3) {
            const float* xrow = embed + quad * 8;
            f32x4 ax0 = {}, ax1 = {}, ax2 = {};
#pragma unroll
            for (int ks = 0; ks < 32; ++ks) {
                bf16x8 xa = cvt8(xrow + ks * 32);
                bf16x8 w0 = *(const bf16x8*)(su.s.WxS + (l15)      * WXS_LD + ks * 32 + quad * 8);
                bf16x8 w1 = *(const bf16x8*)(su.s.WxS + (16 + l15) * WXS_LD + ks * 32 + quad * 8);
                bf16x8 w2 = *(const bf16x8*)(su.s.WxS + (32 + l15) * WXS_LD + ks * 32 + quad * 8);
                ax0 = mfma16(xa, w0, ax0);
                ax1 = mfma16(xa, w1, ax1);
                ax2 = mfma16(xa, w2, ax2);
            }
#pragma unroll
            for (int i = 0; i < 4; ++i) {
                su.s.xpx[0][(quad * 4 + i) * 17 + l15]      = ax0[i];
                su.s.xpx[0][(16 + quad * 4 + i) * 17 + l15] = ax1[i];
                su.s.xpx[0][(32 + quad * 4 + i) * 17 + l15] = ax2[i];
            }
        }

        for (int t = 0; t < T_SZ; ++t) {
            // ---- waves 0..2: hp = h_{t-1} @ Wh slice, split-precision A ----
            if (wave < 3) {
                f32x4 a0 = {}, a1 = {};
                if (t == 0) {
                    const float* hrow = h0 + quad * 8;
#pragma unroll
                    for (int ks = 0; ks < 32; ++ks) {
                        bfpair h8 = split8(hrow + ks * 32);
                        a0 = mfma16(h8.hi, breg[ks], a0);
                        a1 = mfma16(h8.lo, breg[ks], a1);
                    }
                } else {
                    const uint32_t* hrow = ghs
                        + ((size_t)(mhalf * 16 + l15) * T_SZ + (t - 1)) * D_DIM + quad * 8;
#pragma unroll
                    for (int ks = 0; ks < 32; ++ks) {
                        bfpair h8 = unpack8(hrow + ks * 32);
                        a0 = mfma16(h8.hi, breg[ks], a0);
                        a1 = mfma16(h8.lo, breg[ks], a1);
                    }
                }
                a0 = a0 + a1;
#pragma unroll
                for (int i = 0; i < 4; ++i)
                    su.s.hpx[(wave * 16 + quad * 4 + i) * 17 + l15] = a0[i];
            }

            // ---- wave 3: xp(t+1), off critical path ----
            if (wave == 3 && t < U_SZ) {
                const int tok = y[(mhalf * 16 + l15) * U_SZ + t] & 1023;
                const float* xrow = embed + (size_t)tok * D_DIM + quad * 8;
                const int p = (t + 1) & 1;
                f32x4 ax0 = {}, ax1 = {}, ax2 = {};
#pragma unroll
                for (int ks = 0; ks < 32; ++ks) {
                    bf16x8 xa = cvt8(xrow + ks * 32);
                    bf16x8 w0 = *(const bf16x8*)(su.s.WxS + (l15)      * WXS_LD + ks * 32 + quad * 8);
                    bf16x8 w1 = *(const bf16x8*)(su.s.WxS + (16 + l15) * WXS_LD + ks * 32 + quad * 8);
                    bf16x8 w2 = *(const bf16x8*)(su.s.WxS + (32 + l15) * WXS_LD + ks * 32 + quad * 8);
                    ax0 = mfma16(xa, w0, ax0);
                    ax1 = mfma16(xa, w1, ax1);
                    ax2 = mfma16(xa, w2, ax2);
                }
#pragma unroll
                for (int i = 0; i < 4; ++i) {
                    su.s.xpx[p][(quad * 4 + i) * 17 + l15]      = ax0[i];
                    su.s.xpx[p][(16 + quad * 4 + i) * 17 + l15] = ax1[i];
                    su.s.xpx[p][(32 + quad * 4 + i) * 17 + l15] = ax2[i];
                }
            }
            __syncthreads();

            // ---- gates: one (gb, gn) per thread; publish packed hi/lo h ----
            {
                const int p = t & 1;
                const float xz = su.s.xpx[p][(gml)      * 17 + nl] + su.s.bxs[nl];
                const float xr = su.s.xpx[p][(16 + gml) * 17 + nl] + su.s.bxs[16 + nl];
                const float xh = su.s.xpx[p][(32 + gml) * 17 + nl] + su.s.bxs[32 + nl];
                const float hz = su.s.hpx[(gml)      * 17 + nl] + su.s.bhs[nl];
                const float hr = su.s.hpx[(16 + gml) * 17 + nl] + su.s.bhs[16 + nl];
                const float hh = su.s.hpx[(32 + gml) * 17 + nl] + su.s.bhs[32 + nl];
                const float z  = 1.f / (1.f + __expf(-(xz + hz)));
                const float r  = 1.f / (1.f + __expf(-(xr + hr)));
                const float pa = xh + r * hh;
                const float hc = 1.f - 2.f / (__expf(2.f * pa) + 1.f);   // tanh(pa)
                const float hn = z * hold + (1.f - z) * hc;
                hold = hn;
                union { uint16_t u[2]; uint32_t w; } pk;
                const bf16 hi = (bf16)hn;
                const bf16 lo = (bf16)(hn - (float)hi);
                pk.u[0] = __builtin_bit_cast(uint16_t, hi);
                pk.u[1] = __builtin_bit_cast(uint16_t, lo);
                uint32_t old = __hip_atomic_exchange(
                    ghs + ((size_t)gb * T_SZ + t) * D_DIM + gn, pk.w,
                    __ATOMIC_RELAXED, AGENT);
                pkjunk ^= old;
            }

            // ---- zero-RMW device barrier: publish h_t (ALL steps now, so
            //      go reaches T_SZ = "scan fully done" for the consumers) ----
            {
                __syncthreads();   // s_waitcnt vmcnt(0) first: drains exchanges
                const int tv = t + 1;
                if (blockIdx.x == 0) {
                    if (wave == 0) {
                        int ok;
                        do {
                            const int s1 = __hip_atomic_load(slots + lane * 4,
                                                             __ATOMIC_RELAXED, AGENT);
                            const int s2 = __hip_atomic_load(slots + (lane + 64) * 4,
                                                             __ATOMIC_RELAXED, AGENT);
                            ok = (lane == 0 || s1 >= tv) && (s2 >= tv);
                        } while (!__all(ok));
                        if (lane < 8)
                            __hip_atomic_store(go + lane * 16, tv,
                                               __ATOMIC_RELAXED, AGENT);
                    }
                } else {
                    if (tid == 0) {
                        __hip_atomic_store(slots + blockIdx.x * 4, tv,
                                           __ATOMIC_RELAXED, AGENT);
                        while (__hip_atomic_load(go + (blockIdx.x & 7) * 16,
                                                 __ATOMIC_RELAXED, AGENT) < tv) {}
                    }
                }
                __syncthreads();
            }
        }

        // consume pkjunk so the exchanges keep their returning form
        if (pkjunk == 0xDEADBEEFu) flags[1023] = 1;

    } else {
        // =================== consumer path: streamed output GEMM ============
        const uint32_t* Cw = (const uint32_t*)ghs;
        float* Cf = (float*)ghs;

        for (int c = (int)blockIdx.x - 128; c < NCHUNK; c += 128) {
            // chunk rows r0..r0+31; max t among them (chunks may cross a
            // batch boundary, in which case they contain t = T_SZ-1)
            const int t0   = (c * 32) % T_SZ;
            const int tmax = (t0 + 31 <= T_SZ - 1) ? (t0 + 31) : (T_SZ - 1);
            int need = tmax + 2; if (need > T_SZ) need = T_SZ;

            if (tid == 0) {
                while (__hip_atomic_load(go + (c & 7) * 16,
                                         __ATOMIC_RELAXED, AGENT) < need)
                    __builtin_amdgcn_s_sleep(4);
            }
            __syncthreads();   // gate visible; prior chunk's MFMA reads done

            const size_t r0 = (size_t)c * 32;
            for (int idx = tid; idx < 32 * 128; idx += 256) {
                const int r = idx >> 7, ch = idx & 127;
                bfpair p = unpack8(Cw + (r0 + r) * D_DIM + ch * 8);
                *(bf16x8*)(su.g.Ah + r * A_LD + ch * 8) = p.hi;
                *(bf16x8*)(su.g.Al + r * A_LD + ch * 8) = p.lo;
            }
            __syncthreads();

            f32x4 acc[2][16] = {};
            const int nbase = wave * 256;
            for (int ks = 0; ks < 32; ++ks) {
                bf16x8 a0h = *(const bf16x8*)(su.g.Ah + (l15)      * A_LD + ks * 32 + quad * 8);
                bf16x8 a0l = *(const bf16x8*)(su.g.Al + (l15)      * A_LD + ks * 32 + quad * 8);
                bf16x8 a1h = *(const bf16x8*)(su.g.Ah + (16 + l15) * A_LD + ks * 32 + quad * 8);
                bf16x8 a1l = *(const bf16x8*)(su.g.Al + (16 + l15) * A_LD + ks * 32 + quad * 8);
#pragma unroll
                for (int nt = 0; nt < 16; ++nt) {
                    const size_t boff = (size_t)(nbase + nt * 16 + l15) * D_DIM + ks * 32 + quad * 8;
                    bf16x8 bhv = *(const bf16x8*)(WdTh + boff);
                    bf16x8 blv = *(const bf16x8*)(WdTl + boff);
                    acc[0][nt] = mfma16(a0h, bhv, acc[0][nt]);
                    acc[0][nt] = mfma16(a0l, bhv, acc[0][nt]);
                    acc[0][nt] = mfma16(a0h, blv, acc[0][nt]);
                    acc[1][nt] = mfma16(a1h, bhv, acc[1][nt]);
                    acc[1][nt] = mfma16(a1l, bhv, acc[1][nt]);
                    acc[1][nt] = mfma16(a1h, blv, acc[1][nt]);
                }
            }

#pragma unroll
            for (int nt = 0; nt < 16; ++nt) {
                const int col = nbase + nt * 16 + l15;
                const float bvl = bd[col];
#pragma unroll
                for (int mt = 0; mt < 2; ++mt)
#pragma unroll
                    for (int i = 0; i < 4; ++i)
                        Cf[(r0 + mt * 16 + quad * 4 + i) * D_DIM + col] =
                            acc[mt][nt][i] + bvl;
            }
        }
    }
}

// ---------------------------------------------------------------------------
extern "C" void kernel_launch(void* const* d_in, const int* in_sizes, int n_in,
                              void* d_out, int out_size, void* d_ws, size_t ws_size,
                              hipStream_t stream) {
    (void)in_sizes; (void)n_in; (void)out_size; (void)ws_size;
    const int*   y     = (const int*)  d_in[0];
    const float* embed = (const float*)d_in[1];
    const float* Wx    = (const float*)d_in[2];
    const float* Wh    = (const float*)d_in[3];
    const float* bx    = (const float*)d_in[4];
    const float* bh    = (const float*)d_in[5];
    const float* Wd    = (const float*)d_in[6];
    const float* bd    = (const float*)d_in[7];
    const float* h0    = (const float*)d_in[8];
    float* out = (float*)d_out;

    // workspace: WdT hi/lo (2+2 MB) + flags (8 KB)
    bf16* WdTh = (bf16*)d_ws;
    bf16* WdTl = WdTh + (size_t)D_DIM * D_DIM;
    int* flags = (int*)((char*)d_ws + (size_t)D_DIM * D_DIM * 4);

    hipMemsetAsync(flags, 0, 8192, stream);

    transpose_split<<<dim3(D_DIM / 32, D_DIM / 32), dim3(32, 8), 0, stream>>>(
        Wd, WdTh, WdTl, D_DIM, D_DIM);

    // Fused: GRU scan (blocks 0-127) + streamed in-place output GEMM
    // (blocks 128-255), gated on the scan's go lines.
    gru_scan<<<256, 256, 0, stream>>>(Wx, Wh, bx, bh, h0, embed, y,
                                      (uint32_t*)out, flags, WdTh, WdTl, bd);
}

// Round 5
// 7697.709 us; speedup vs baseline: 1.1766x; 1.0059x over previous
//
#include <hip/hip_runtime.h>
#include <hip/hip_bf16.h>
#include <cstdint>

typedef __bf16 bf16;
typedef __bf16 bf16x8 __attribute__((ext_vector_type(8)));
typedef float  f32x4  __attribute__((ext_vector_type(4)));
typedef uint32_t u32x4 __attribute__((ext_vector_type(4)));

#define D_DIM   1024
#define ND      3072
#define B_SZ    32
#define U_SZ    512
#define T_SZ    513
#define M_REAL  (B_SZ * T_SZ)   // 16416
#define WXS_LD  1032            // padded k-stride
#define A_LD    1032

#define AGENT __HIP_MEMORY_SCOPE_AGENT

__device__ __forceinline__ f32x4 mfma16(bf16x8 a, bf16x8 b, f32x4 c) {
    return __builtin_amdgcn_mfma_f32_16x16x32_bf16(a, b, c, 0, 0, 0);
}

struct bfpair { bf16x8 hi, lo; };

// split 8 consecutive fp32 into bf16 hi + bf16 residual lo
__device__ __forceinline__ bfpair split8(const float* p) {
    f32x4 a = *(const f32x4*)p;
    f32x4 b = *(const f32x4*)(p + 4);
    bfpair r;
#pragma unroll
    for (int j = 0; j < 4; ++j) {
        r.hi[j] = (bf16)a[j];
        r.lo[j] = (bf16)(a[j] - (float)r.hi[j]);
        r.hi[4 + j] = (bf16)b[j];
        r.lo[4 + j] = (bf16)(b[j] - (float)r.hi[4 + j]);
    }
    return r;
}

// convert 8 consecutive fp32 to bf16
__device__ __forceinline__ bf16x8 cvt8(const float* p) {
    f32x4 a = *(const f32x4*)p;
    f32x4 b = *(const f32x4*)(p + 4);
    bf16x8 r;
#pragma unroll
    for (int j = 0; j < 4; ++j) { r[j] = (bf16)a[j]; r[4 + j] = (bf16)b[j]; }
    return r;
}

// unpack 8 packed uint32 (hi bf16 | lo bf16 << 16) -> hi8, lo8 via v_perm
__device__ __forceinline__ bfpair unpack8(const uint32_t* p) {
    u32x4 a = *(const u32x4*)p;
    u32x4 b = *(const u32x4*)(p + 4);
    union { uint32_t u[4]; bf16x8 v; } H, L;
    H.u[0] = __builtin_amdgcn_perm(a.y, a.x, 0x05040100u);
    H.u[1] = __builtin_amdgcn_perm(a.w, a.z, 0x05040100u);
    H.u[2] = __builtin_amdgcn_perm(b.y, b.x, 0x05040100u);
    H.u[3] = __builtin_amdgcn_perm(b.w, b.z, 0x05040100u);
    L.u[0] = __builtin_amdgcn_perm(a.y, a.x, 0x07060302u);
    L.u[1] = __builtin_amdgcn_perm(a.w, a.z, 0x07060302u);
    L.u[2] = __builtin_amdgcn_perm(b.y, b.x, 0x07060302u);
    L.u[3] = __builtin_amdgcn_perm(b.w, b.z, 0x07060302u);
    bfpair r; r.hi = H.v; r.lo = L.v;
    return r;
}

// ---------------------------------------------------------------------------
// Transpose fp32 Wd [K][N] -> bf16 hi/lo planes WdT[N][K]
// ---------------------------------------------------------------------------
__global__ void transpose_split(const float* __restrict__ in,
                                bf16* __restrict__ out_hi, bf16* __restrict__ out_lo,
                                int R, int C) {
    __shared__ float tile[32][33];
    const int c0 = blockIdx.x * 32, r0 = blockIdx.y * 32;
    const int tx = threadIdx.x, ty = threadIdx.y;   // 32 x 8
    for (int i = 0; i < 32; i += 8)
        tile[ty + i][tx] = in[(size_t)(r0 + ty + i) * C + c0 + tx];
    __syncthreads();
    for (int i = 0; i < 32; i += 8) {
        const float v  = tile[tx][ty + i];
        const bf16  hi = (bf16)v;
        out_hi[(size_t)(c0 + ty + i) * R + r0 + tx] = hi;
        out_lo[(size_t)(c0 + ty + i) * R + r0 + tx] = (bf16)(v - (float)hi);
    }
}

// ---------------------------------------------------------------------------
// GRU scan (R11) = R6 structure verbatim, ONE change: one-hop barrier.
//   128 persistent WGs x 256 threads; block = (mhalf, 16-dim slice).
//   R6 (two-hop): arrival -> block0 leader sweep (+1 RT) -> go store (+1 RT)
//     -> spinner read (+1 RT). R11 (one-hop): every block's wave 0 sweeps
//     all 128 slots directly (lane covers {lane, lane+64}, own slot
//     special-cased); release = last arrival + 1 RT + s_barrier. Saves ~2
//     dependent MALL round trips per step. Poll traffic ~16K loads/iter
//     device-wide; R7-R9 showed no correlation between poll traffic and
//     step time, so this bets only on the hop count.
// ---------------------------------------------------------------------------
__global__ __launch_bounds__(256, 1)
void gru_scan(const float* __restrict__ Wx,    const float* __restrict__ Wh,
              const float* __restrict__ bx,    const float* __restrict__ bh,
              const float* __restrict__ h0,    const float* __restrict__ embed,
              const int* __restrict__ y,       uint32_t* __restrict__ ghs,
              int* __restrict__ flags)
{
    __shared__ __align__(16) bf16 WxS[48 * WXS_LD];  // [c = gate*16+cl][k]
    __shared__ float hpx[48 * 17];
    __shared__ float xpx[2][48 * 17];
    __shared__ float bhs[48], bxs[48];

    const int tid  = threadIdx.x;
    const int wave = tid >> 6, lane = tid & 63;
    const int quad = lane >> 4, l15 = lane & 15;
    const int mhalf = blockIdx.x & 1;
    const int n0 = (blockIdx.x >> 1) * 16;
    int* slots = flags;          // slot for block b at flags[b*4]  (16-B stride)

    // ---- one-time: gather Wx slice [48 cols][1024 k] from fp32 Wx[k][3D] ----
    for (int idx = tid; idx < 3 * 1024 * 16; idx += 256) {
        const int cl = idx & 15;
        const int k  = (idx >> 4) & 1023;
        const int g  = idx >> 14;            // 0..2
        WxS[(g * 16 + cl) * WXS_LD + k] = (bf16)Wx[(size_t)k * ND + g * D_DIM + n0 + cl];
    }
    if (tid < 48) {
        bhs[tid] = bh[(tid >> 4) * D_DIM + n0 + (tid & 15)];
        bxs[tid] = bx[(tid >> 4) * D_DIM + n0 + (tid & 15)];
    }

    // ---- one-time: gather Wh gate-slice into registers (waves 0..2) ----
    bf16x8 breg[32];
    if (wave < 3) {
#pragma unroll
        for (int ks = 0; ks < 32; ++ks) {
            bf16x8 v;
#pragma unroll
            for (int j = 0; j < 8; ++j)
                v[j] = (bf16)Wh[(size_t)(ks * 32 + quad * 8 + j) * ND
                                + wave * D_DIM + n0 + l15];
            breg[ks] = v;
        }
    }

    // gate-phase identity: one (batch, dim) output per thread
    const int gml = tid >> 4, nl = tid & 15;
    const int gb  = mhalf * 16 + gml;
    const int gn  = n0 + nl;
    float hold = h0[gn];
    uint32_t pkjunk = 0;

    __syncthreads();

    // ---- pre-loop: xp(0), all tokens NULL (embed row 0) -> xpx[0] ----
    if (wave == 3) {
        const float* xrow = embed + quad * 8;
        f32x4 ax0 = {}, ax1 = {}, ax2 = {};
#pragma unroll
        for (int ks = 0; ks < 32; ++ks) {
            bf16x8 xa = cvt8(xrow + ks * 32);
            bf16x8 w0 = *(const bf16x8*)(WxS + (l15)      * WXS_LD + ks * 32 + quad * 8);
            bf16x8 w1 = *(const bf16x8*)(WxS + (16 + l15) * WXS_LD + ks * 32 + quad * 8);
            bf16x8 w2 = *(const bf16x8*)(WxS + (32 + l15) * WXS_LD + ks * 32 + quad * 8);
            ax0 = mfma16(xa, w0, ax0);
            ax1 = mfma16(xa, w1, ax1);
            ax2 = mfma16(xa, w2, ax2);
        }
#pragma unroll
        for (int i = 0; i < 4; ++i) {
            xpx[0][(quad * 4 + i) * 17 + l15]      = ax0[i];
            xpx[0][(16 + quad * 4 + i) * 17 + l15] = ax1[i];
            xpx[0][(32 + quad * 4 + i) * 17 + l15] = ax2[i];
        }
    }

    for (int t = 0; t < T_SZ; ++t) {
        // ---- waves 0..2: hp = h_{t-1} @ Wh slice, split-precision A ----
        if (wave < 3) {
            f32x4 a0 = {}, a1 = {};
            if (t == 0) {
                const float* hrow = h0 + quad * 8;
#pragma unroll
                for (int ks = 0; ks < 32; ++ks) {
                    bfpair h8 = split8(hrow + ks * 32);
                    a0 = mfma16(h8.hi, breg[ks], a0);
                    a1 = mfma16(h8.lo, breg[ks], a1);
                }
            } else {
                const uint32_t* hrow = ghs
                    + ((size_t)(mhalf * 16 + l15) * T_SZ + (t - 1)) * D_DIM + quad * 8;
#pragma unroll
                for (int ks = 0; ks < 32; ++ks) {
                    bfpair h8 = unpack8(hrow + ks * 32);
                    a0 = mfma16(h8.hi, breg[ks], a0);
                    a1 = mfma16(h8.lo, breg[ks], a1);
                }
            }
            a0 = a0 + a1;
#pragma unroll
            for (int i = 0; i < 4; ++i)
                hpx[(wave * 16 + quad * 4 + i) * 17 + l15] = a0[i];
        }

        // ---- wave 3: xp(t+1), off critical path ----
        if (wave == 3 && t < U_SZ) {
            const int tok = y[(mhalf * 16 + l15) * U_SZ + t] & 1023;  // token at step t+1
            const float* xrow = embed + (size_t)tok * D_DIM + quad * 8;
            const int p = (t + 1) & 1;
            f32x4 ax0 = {}, ax1 = {}, ax2 = {};
#pragma unroll
            for (int ks = 0; ks < 32; ++ks) {
                bf16x8 xa = cvt8(xrow + ks * 32);
                bf16x8 w0 = *(const bf16x8*)(WxS + (l15)      * WXS_LD + ks * 32 + quad * 8);
                bf16x8 w1 = *(const bf16x8*)(WxS + (16 + l15) * WXS_LD + ks * 32 + quad * 8);
                bf16x8 w2 = *(const bf16x8*)(WxS + (32 + l15) * WXS_LD + ks * 32 + quad * 8);
                ax0 = mfma16(xa, w0, ax0);
                ax1 = mfma16(xa, w1, ax1);
                ax2 = mfma16(xa, w2, ax2);
            }
#pragma unroll
            for (int i = 0; i < 4; ++i) {
                xpx[p][(quad * 4 + i) * 17 + l15]      = ax0[i];
                xpx[p][(16 + quad * 4 + i) * 17 + l15] = ax1[i];
                xpx[p][(32 + quad * 4 + i) * 17 + l15] = ax2[i];
            }
        }
        __syncthreads();

        // ---- gates: one (gb, gn) per thread; publish packed hi/lo h ----
        {
            const int p = t & 1;
            const float xz = xpx[p][(gml)      * 17 + nl] + bxs[nl];
            const float xr = xpx[p][(16 + gml) * 17 + nl] + bxs[16 + nl];
            const float xh = xpx[p][(32 + gml) * 17 + nl] + bxs[32 + nl];
            const float hz = hpx[(gml)      * 17 + nl] + bhs[nl];
            const float hr = hpx[(16 + gml) * 17 + nl] + bhs[16 + nl];
            const float hh = hpx[(32 + gml) * 17 + nl] + bhs[32 + nl];
            const float z  = 1.f / (1.f + __expf(-(xz + hz)));
            const float r  = 1.f / (1.f + __expf(-(xr + hr)));
            const float pa = xh + r * hh;
            const float hc = 1.f - 2.f / (__expf(2.f * pa) + 1.f);   // tanh(pa)
            const float hn = z * hold + (1.f - z) * hc;
            hold = hn;
            union { uint16_t u[2]; uint32_t w; } pk;
            const bf16 hi = (bf16)hn;
            const bf16 lo = (bf16)(hn - (float)hi);
            pk.u[0] = __builtin_bit_cast(uint16_t, hi);
            pk.u[1] = __builtin_bit_cast(uint16_t, lo);
            uint32_t old = __hip_atomic_exchange(
                ghs + ((size_t)gb * T_SZ + t) * D_DIM + gn, pk.w,
                __ATOMIC_RELAXED, AGENT);
            pkjunk ^= old;
        }

        // ---- one-hop zero-RMW device barrier: publish h_t ----
        if (t + 1 < T_SZ) {
            __syncthreads();   // s_waitcnt vmcnt(0) first: drains exchanges
            const int tv = t + 1;
            if (wave == 0) {
                if (lane == 0)
                    __hip_atomic_store(slots + blockIdx.x * 4, tv,
                                       __ATOMIC_RELAXED, AGENT);
                // every block sweeps all 128 slots itself: lane covers
                // {lane, lane+64}; own slot special-cased (no wait on own
                // store's round trip). Release = last arrival + 1 RT.
                int ok;
                do {
                    const int s1 = __hip_atomic_load(slots + lane * 4,
                                                     __ATOMIC_RELAXED, AGENT);
                    const int s2 = __hip_atomic_load(slots + (lane + 64) * 4,
                                                     __ATOMIC_RELAXED, AGENT);
                    ok = (lane == blockIdx.x      || s1 >= tv) &&
                         (lane + 64 == blockIdx.x || s2 >= tv);
                } while (!__all(ok));
            }
            __syncthreads();
        }
    }

    // consume pkjunk so the exchanges keep their returning form
    if (pkjunk == 0xDEADBEEFu) flags[1023] = 1;
}

// ---------------------------------------------------------------------------
// In-place row-block GEMM: rows (packed hi/lo h) -> fp32 out rows.
// ---------------------------------------------------------------------------
__global__ __launch_bounds__(256, 1)
void gemm_rows_inplace(float* __restrict__ C,
                       const bf16* __restrict__ WdTh, const bf16* __restrict__ WdTl,
                       const float* __restrict__ bd)
{
    __shared__ __align__(16) bf16 Ah[32 * A_LD];
    __shared__ __align__(16) bf16 Al[32 * A_LD];
    const int tid  = threadIdx.x;
    const int wave = tid >> 6, lane = tid & 63;
    const int quad = lane >> 4, l15 = lane & 15;
    const size_t r0 = (size_t)blockIdx.x * 32;
    const uint32_t* Cw = (const uint32_t*)C;

    for (int idx = tid; idx < 32 * 128; idx += 256) {
        const int r = idx >> 7, ch = idx & 127;
        bfpair p = unpack8(Cw + (r0 + r) * D_DIM + ch * 8);
        *(bf16x8*)(Ah + r * A_LD + ch * 8) = p.hi;
        *(bf16x8*)(Al + r * A_LD + ch * 8) = p.lo;
    }
    __syncthreads();

    f32x4 acc[2][16] = {};
    const int nbase = wave * 256;
    for (int ks = 0; ks < 32; ++ks) {
        bf16x8 a0h = *(const bf16x8*)(Ah + (l15)      * A_LD + ks * 32 + quad * 8);
        bf16x8 a0l = *(const bf16x8*)(Al + (l15)      * A_LD + ks * 32 + quad * 8);
        bf16x8 a1h = *(const bf16x8*)(Ah + (16 + l15) * A_LD + ks * 32 + quad * 8);
        bf16x8 a1l = *(const bf16x8*)(Al + (16 + l15) * A_LD + ks * 32 + quad * 8);
#pragma unroll
        for (int nt = 0; nt < 16; ++nt) {
            const size_t boff = (size_t)(nbase + nt * 16 + l15) * D_DIM + ks * 32 + quad * 8;
            bf16x8 bhv = *(const bf16x8*)(WdTh + boff);
            bf16x8 blv = *(const bf16x8*)(WdTl + boff);
            acc[0][nt] = mfma16(a0h, bhv, acc[0][nt]);
            acc[0][nt] = mfma16(a0l, bhv, acc[0][nt]);
            acc[0][nt] = mfma16(a0h, blv, acc[0][nt]);
            acc[1][nt] = mfma16(a1h, bhv, acc[1][nt]);
            acc[1][nt] = mfma16(a1l, bhv, acc[1][nt]);
            acc[1][nt] = mfma16(a1h, blv, acc[1][nt]);
        }
    }

#pragma unroll
    for (int nt = 0; nt < 16; ++nt) {
        const int col = nbase + nt * 16 + l15;
        const float bvl = bd[col];
#pragma unroll
        for (int mt = 0; mt < 2; ++mt)
#pragma unroll
            for (int i = 0; i < 4; ++i)
                C[(r0 + mt * 16 + quad * 4 + i) * D_DIM + col] =
                    acc[mt][nt][i] + bvl;
    }
}

// ---------------------------------------------------------------------------
extern "C" void kernel_launch(void* const* d_in, const int* in_sizes, int n_in,
                              void* d_out, int out_size, void* d_ws, size_t ws_size,
                              hipStream_t stream) {
    (void)in_sizes; (void)n_in; (void)out_size; (void)ws_size;
    const int*   y     = (const int*)  d_in[0];
    const float* embed = (const float*)d_in[1];
    const float* Wx    = (const float*)d_in[2];
    const float* Wh    = (const float*)d_in[3];
    const float* bx    = (const float*)d_in[4];
    const float* bh    = (const float*)d_in[5];
    const float* Wd    = (const float*)d_in[6];
    const float* bd    = (const float*)d_in[7];
    const float* h0    = (const float*)d_in[8];
    float* out = (float*)d_out;

    // workspace: WdT hi/lo (2+2 MB) + flags (8 KB)
    bf16* WdTh = (bf16*)d_ws;
    bf16* WdTl = WdTh + (size_t)D_DIM * D_DIM;
    int* flags = (int*)((char*)d_ws + (size_t)D_DIM * D_DIM * 4);

    hipMemsetAsync(flags, 0, 8192, stream);

    transpose_split<<<dim3(D_DIM / 32, D_DIM / 32), dim3(32, 8), 0, stream>>>(
        Wd, WdTh, WdTl, D_DIM, D_DIM);

    // GRU scan with fused input projections; packed h history -> d_out rows
    gru_scan<<<128, 256, 0, stream>>>(Wx, Wh, bx, bh, h0, embed, y,
                                      (uint32_t*)out, flags);

    // In-place: out rows = h rows @ Wd + bd
    gemm_rows_inplace<<<M_REAL / 32, 256, 0, stream>>>(out, WdTh, WdTl, bd);
}

// Round 6
// 7317.338 us; speedup vs baseline: 1.2377x; 1.0520x over previous
//
#include <hip/hip_runtime.h>
#include <hip/hip_bf16.h>
#include <cstdint>

typedef __bf16 bf16;
typedef __bf16 bf16x8 __attribute__((ext_vector_type(8)));
typedef float  f32x4  __attribute__((ext_vector_type(4)));
typedef uint32_t u32x4 __attribute__((ext_vector_type(4)));

#define D_DIM   1024
#define ND      3072
#define B_SZ    32
#define U_SZ    512
#define T_SZ    513
#define M_REAL  (B_SZ * T_SZ)   // 16416
#define WXS_LD  1032            // padded k-stride
#define A_LD    1032

#define AGENT __HIP_MEMORY_SCOPE_AGENT

__device__ __forceinline__ f32x4 mfma16(bf16x8 a, bf16x8 b, f32x4 c) {
    return __builtin_amdgcn_mfma_f32_16x16x32_bf16(a, b, c, 0, 0, 0);
}

struct bfpair { bf16x8 hi, lo; };

// split 8 consecutive fp32 into bf16 hi + bf16 residual lo
__device__ __forceinline__ bfpair split8(const float* p) {
    f32x4 a = *(const f32x4*)p;
    f32x4 b = *(const f32x4*)(p + 4);
    bfpair r;
#pragma unroll
    for (int j = 0; j < 4; ++j) {
        r.hi[j] = (bf16)a[j];
        r.lo[j] = (bf16)(a[j] - (float)r.hi[j]);
        r.hi[4 + j] = (bf16)b[j];
        r.lo[4 + j] = (bf16)(b[j] - (float)r.hi[4 + j]);
    }
    return r;
}

// convert 8 consecutive fp32 to bf16
__device__ __forceinline__ bf16x8 cvt8(const float* p) {
    f32x4 a = *(const f32x4*)p;
    f32x4 b = *(const f32x4*)(p + 4);
    bf16x8 r;
#pragma unroll
    for (int j = 0; j < 4; ++j) { r[j] = (bf16)a[j]; r[4 + j] = (bf16)b[j]; }
    return r;
}

// unpack 8 packed uint32 (hi bf16 | lo bf16 << 16) -> hi8, lo8 via v_perm
__device__ __forceinline__ bfpair unpack8(const uint32_t* p) {
    u32x4 a = *(const u32x4*)p;
    u32x4 b = *(const u32x4*)(p + 4);
    union { uint32_t u[4]; bf16x8 v; } H, L;
    H.u[0] = __builtin_amdgcn_perm(a.y, a.x, 0x05040100u);
    H.u[1] = __builtin_amdgcn_perm(a.w, a.z, 0x05040100u);
    H.u[2] = __builtin_amdgcn_perm(b.y, b.x, 0x05040100u);
    H.u[3] = __builtin_amdgcn_perm(b.w, b.z, 0x05040100u);
    L.u[0] = __builtin_amdgcn_perm(a.y, a.x, 0x07060302u);
    L.u[1] = __builtin_amdgcn_perm(a.w, a.z, 0x07060302u);
    L.u[2] = __builtin_amdgcn_perm(b.y, b.x, 0x07060302u);
    L.u[3] = __builtin_amdgcn_perm(b.w, b.z, 0x07060302u);
    bfpair r; r.hi = H.v; r.lo = L.v;
    return r;
}

// ---------------------------------------------------------------------------
// Transpose fp32 Wd [K][N] -> bf16 hi/lo planes in MFMA-FRAGMENT ORDER (R12):
//   P[((col/16)*32 + row/32)*512 + ((row>>3)&3)*128 + (col&15)*8 + (row&7)]
//   i.e. for each (16-col group cg, 32-k slice ks) the 64 lanes' bf16x8
//   fragments are contiguous (1 KB per plane). This makes every B-frag load
//   in the GEMM a fully coalesced wave read (R6 layout: lanes 2 KB apart ->
//   64 line requests per load, 2x over-fetch, ~3.4 TB/s effective).
// ---------------------------------------------------------------------------
__global__ void transpose_split(const float* __restrict__ in,
                                bf16* __restrict__ out_hi, bf16* __restrict__ out_lo,
                                int R, int C) {
    __shared__ float tile[32][33];
    const int c0 = blockIdx.x * 32, r0 = blockIdx.y * 32;
    const int tx = threadIdx.x, ty = threadIdx.y;   // 32 x 8
    for (int i = 0; i < 32; i += 8)
        tile[ty + i][tx] = in[(size_t)(r0 + ty + i) * C + c0 + tx];
    __syncthreads();
    for (int i = 0; i < 32; i += 8) {
        const float v  = tile[tx][ty + i];
        const bf16  hi = (bf16)v;
        const int col = c0 + ty + i;      // output col (N)
        const int row = r0 + tx;          // output row (K)
        const size_t idx = ((size_t)((col >> 4) * 32 + (row >> 5)) << 9)
                         + (((row >> 3) & 3) << 7) + ((col & 15) << 3) + (row & 7);
        out_hi[idx] = hi;
        out_lo[idx] = (bf16)(v - (float)hi);
    }
}

// ---------------------------------------------------------------------------
// GRU scan — R6 structure byte-identical (measured best: 6885 us).
//   128 persistent WGs x 256 threads; block = (mhalf, 16-dim slice).
//   Zero-RMW two-hop barrier: arrive = relaxed store to per-block slot;
//   block 0 wave 0 sweeps all 128 slots in parallel, then stores go=t+1
//   replicated on 8 lines; others spin on their go line.
//   (R11's one-hop all-blocks sweep measured SLOWER: +0.6 us/step from
//   hot-line contention. R7-R9 restructures all regressed. Do not touch.)
// ---------------------------------------------------------------------------
__global__ __launch_bounds__(256, 1)
void gru_scan(const float* __restrict__ Wx,    const float* __restrict__ Wh,
              const float* __restrict__ bx,    const float* __restrict__ bh,
              const float* __restrict__ h0,    const float* __restrict__ embed,
              const int* __restrict__ y,       uint32_t* __restrict__ ghs,
              int* __restrict__ flags)
{
    __shared__ __align__(16) bf16 WxS[48 * WXS_LD];  // [c = gate*16+cl][k]
    __shared__ float hpx[48 * 17];
    __shared__ float xpx[2][48 * 17];
    __shared__ float bhs[48], bxs[48];

    const int tid  = threadIdx.x;
    const int wave = tid >> 6, lane = tid & 63;
    const int quad = lane >> 4, l15 = lane & 15;
    const int mhalf = blockIdx.x & 1;
    const int n0 = (blockIdx.x >> 1) * 16;
    int* slots = flags;          // slot for block b at flags[b*4]  (16-B stride)
    int* go    = flags + 512;    // go line j at flags[512 + j*16], j=0..7

    // ---- one-time: gather Wx slice [48 cols][1024 k] from fp32 Wx[k][3D] ----
    for (int idx = tid; idx < 3 * 1024 * 16; idx += 256) {
        const int cl = idx & 15;
        const int k  = (idx >> 4) & 1023;
        const int g  = idx >> 14;            // 0..2
        WxS[(g * 16 + cl) * WXS_LD + k] = (bf16)Wx[(size_t)k * ND + g * D_DIM + n0 + cl];
    }
    if (tid < 48) {
        bhs[tid] = bh[(tid >> 4) * D_DIM + n0 + (tid & 15)];
        bxs[tid] = bx[(tid >> 4) * D_DIM + n0 + (tid & 15)];
    }

    // ---- one-time: gather Wh gate-slice into registers (waves 0..2) ----
    bf16x8 breg[32];
    if (wave < 3) {
#pragma unroll
        for (int ks = 0; ks < 32; ++ks) {
            bf16x8 v;
#pragma unroll
            for (int j = 0; j < 8; ++j)
                v[j] = (bf16)Wh[(size_t)(ks * 32 + quad * 8 + j) * ND
                                + wave * D_DIM + n0 + l15];
            breg[ks] = v;
        }
    }

    // gate-phase identity: one (batch, dim) output per thread
    const int gml = tid >> 4, nl = tid & 15;
    const int gb  = mhalf * 16 + gml;
    const int gn  = n0 + nl;
    float hold = h0[gn];
    uint32_t pkjunk = 0;

    __syncthreads();

    // ---- pre-loop: xp(0), all tokens NULL (embed row 0) -> xpx[0] ----
    if (wave == 3) {
        const float* xrow = embed + quad * 8;
        f32x4 ax0 = {}, ax1 = {}, ax2 = {};
#pragma unroll
        for (int ks = 0; ks < 32; ++ks) {
            bf16x8 xa = cvt8(xrow + ks * 32);
            bf16x8 w0 = *(const bf16x8*)(WxS + (l15)      * WXS_LD + ks * 32 + quad * 8);
            bf16x8 w1 = *(const bf16x8*)(WxS + (16 + l15) * WXS_LD + ks * 32 + quad * 8);
            bf16x8 w2 = *(const bf16x8*)(WxS + (32 + l15) * WXS_LD + ks * 32 + quad * 8);
            ax0 = mfma16(xa, w0, ax0);
            ax1 = mfma16(xa, w1, ax1);
            ax2 = mfma16(xa, w2, ax2);
        }
#pragma unroll
        for (int i = 0; i < 4; ++i) {
            xpx[0][(quad * 4 + i) * 17 + l15]      = ax0[i];
            xpx[0][(16 + quad * 4 + i) * 17 + l15] = ax1[i];
            xpx[0][(32 + quad * 4 + i) * 17 + l15] = ax2[i];
        }
    }

    for (int t = 0; t < T_SZ; ++t) {
        // ---- waves 0..2: hp = h_{t-1} @ Wh slice, split-precision A ----
        if (wave < 3) {
            f32x4 a0 = {}, a1 = {};
            if (t == 0) {
                const float* hrow = h0 + quad * 8;
#pragma unroll
                for (int ks = 0; ks < 32; ++ks) {
                    bfpair h8 = split8(hrow + ks * 32);
                    a0 = mfma16(h8.hi, breg[ks], a0);
                    a1 = mfma16(h8.lo, breg[ks], a1);
                }
            } else {
                const uint32_t* hrow = ghs
                    + ((size_t)(mhalf * 16 + l15) * T_SZ + (t - 1)) * D_DIM + quad * 8;
#pragma unroll
                for (int ks = 0; ks < 32; ++ks) {
                    bfpair h8 = unpack8(hrow + ks * 32);
                    a0 = mfma16(h8.hi, breg[ks], a0);
                    a1 = mfma16(h8.lo, breg[ks], a1);
                }
            }
            a0 = a0 + a1;
#pragma unroll
            for (int i = 0; i < 4; ++i)
                hpx[(wave * 16 + quad * 4 + i) * 17 + l15] = a0[i];
        }

        // ---- wave 3: xp(t+1), off critical path ----
        if (wave == 3 && t < U_SZ) {
            const int tok = y[(mhalf * 16 + l15) * U_SZ + t] & 1023;  // token at step t+1
            const float* xrow = embed + (size_t)tok * D_DIM + quad * 8;
            const int p = (t + 1) & 1;
            f32x4 ax0 = {}, ax1 = {}, ax2 = {};
#pragma unroll
            for (int ks = 0; ks < 32; ++ks) {
                bf16x8 xa = cvt8(xrow + ks * 32);
                bf16x8 w0 = *(const bf16x8*)(WxS + (l15)      * WXS_LD + ks * 32 + quad * 8);
                bf16x8 w1 = *(const bf16x8*)(WxS + (16 + l15) * WXS_LD + ks * 32 + quad * 8);
                bf16x8 w2 = *(const bf16x8*)(WxS + (32 + l15) * WXS_LD + ks * 32 + quad * 8);
                ax0 = mfma16(xa, w0, ax0);
                ax1 = mfma16(xa, w1, ax1);
                ax2 = mfma16(xa, w2, ax2);
            }
#pragma unroll
            for (int i = 0; i < 4; ++i) {
                xpx[p][(quad * 4 + i) * 17 + l15]      = ax0[i];
                xpx[p][(16 + quad * 4 + i) * 17 + l15] = ax1[i];
                xpx[p][(32 + quad * 4 + i) * 17 + l15] = ax2[i];
            }
        }
        __syncthreads();

        // ---- gates: one (gb, gn) per thread; publish packed hi/lo h ----
        {
            const int p = t & 1;
            const float xz = xpx[p][(gml)      * 17 + nl] + bxs[nl];
            const float xr = xpx[p][(16 + gml) * 17 + nl] + bxs[16 + nl];
            const float xh = xpx[p][(32 + gml) * 17 + nl] + bxs[32 + nl];
            const float hz = hpx[(gml)      * 17 + nl] + bhs[nl];
            const float hr = hpx[(16 + gml) * 17 + nl] + bhs[16 + nl];
            const float hh = hpx[(32 + gml) * 17 + nl] + bhs[32 + nl];
            const float z  = 1.f / (1.f + __expf(-(xz + hz)));
            const float r  = 1.f / (1.f + __expf(-(xr + hr)));
            const float pa = xh + r * hh;
            const float hc = 1.f - 2.f / (__expf(2.f * pa) + 1.f);   // tanh(pa)
            const float hn = z * hold + (1.f - z) * hc;
            hold = hn;
            union { uint16_t u[2]; uint32_t w; } pk;
            const bf16 hi = (bf16)hn;
            const bf16 lo = (bf16)(hn - (float)hi);
            pk.u[0] = __builtin_bit_cast(uint16_t, hi);
            pk.u[1] = __builtin_bit_cast(uint16_t, lo);
            uint32_t old = __hip_atomic_exchange(
                ghs + ((size_t)gb * T_SZ + t) * D_DIM + gn, pk.w,
                __ATOMIC_RELAXED, AGENT);
            pkjunk ^= old;
        }

        // ---- zero-RMW device barrier: publish h_t ----
        if (t + 1 < T_SZ) {
            __syncthreads();   // s_waitcnt vmcnt(0) first: drains exchanges
            const int tv = t + 1;
            if (blockIdx.x == 0) {
                if (wave == 0) {
                    // parallel sweep: lane covers slots {lane, lane+64};
                    // slot 0 is ourselves (arrived by construction)
                    int ok;
                    do {
                        const int s1 = __hip_atomic_load(slots + lane * 4,
                                                         __ATOMIC_RELAXED, AGENT);
                        const int s2 = __hip_atomic_load(slots + (lane + 64) * 4,
                                                         __ATOMIC_RELAXED, AGENT);
                        ok = (lane == 0 || s1 >= tv) && (s2 >= tv);
                    } while (!__all(ok));
                    if (lane < 8)
                        __hip_atomic_store(go + lane * 16, tv,
                                           __ATOMIC_RELAXED, AGENT);
                }
            } else {
                if (tid == 0) {
                    __hip_atomic_store(slots + blockIdx.x * 4, tv,
                                       __ATOMIC_RELAXED, AGENT);
                    while (__hip_atomic_load(go + (blockIdx.x & 7) * 16,
                                             __ATOMIC_RELAXED, AGENT) < tv) {}
                }
            }
            __syncthreads();
        }
    }

    // consume pkjunk so the exchanges keep their returning form
    if (pkjunk == 0xDEADBEEFu) flags[1023] = 1;
}

// ---------------------------------------------------------------------------
// In-place row-block GEMM: rows (packed hi/lo h) -> fp32 out rows.
// R12: B planes are in fragment order -> every B load is a coalesced 1 KB
// wave read (lane i at base + i*16B) instead of 64 scattered lines.
// ---------------------------------------------------------------------------
__global__ __launch_bounds__(256, 1)
void gemm_rows_inplace(float* __restrict__ C,
                       const bf16* __restrict__ WdTh, const bf16* __restrict__ WdTl,
                       const float* __restrict__ bd)
{
    __shared__ __align__(16) bf16 Ah[32 * A_LD];
    __shared__ __align__(16) bf16 Al[32 * A_LD];
    const int tid  = threadIdx.x;
    const int wave = tid >> 6, lane = tid & 63;
    const int quad = lane >> 4, l15 = lane & 15;
    const size_t r0 = (size_t)blockIdx.x * 32;
    const uint32_t* Cw = (const uint32_t*)C;

    for (int idx = tid; idx < 32 * 128; idx += 256) {
        const int r = idx >> 7, ch = idx & 127;
        bfpair p = unpack8(Cw + (r0 + r) * D_DIM + ch * 8);
        *(bf16x8*)(Ah + r * A_LD + ch * 8) = p.hi;
        *(bf16x8*)(Al + r * A_LD + ch * 8) = p.lo;
    }
    __syncthreads();

    f32x4 acc[2][16] = {};
    for (int ks = 0; ks < 32; ++ks) {
        bf16x8 a0h = *(const bf16x8*)(Ah + (l15)      * A_LD + ks * 32 + quad * 8);
        bf16x8 a0l = *(const bf16x8*)(Al + (l15)      * A_LD + ks * 32 + quad * 8);
        bf16x8 a1h = *(const bf16x8*)(Ah + (16 + l15) * A_LD + ks * 32 + quad * 8);
        bf16x8 a1l = *(const bf16x8*)(Al + (16 + l15) * A_LD + ks * 32 + quad * 8);
#pragma unroll
        for (int nt = 0; nt < 16; ++nt) {
            const int cg = wave * 16 + nt;     // 16-col group 0..63
            const size_t boff = (((size_t)cg * 32 + ks) << 9) + (size_t)lane * 8;
            bf16x8 bhv = *(const bf16x8*)(WdTh + boff);
            bf16x8 blv = *(const bf16x8*)(WdTl + boff);
            acc[0][nt] = mfma16(a0h, bhv, acc[0][nt]);
            acc[0][nt] = mfma16(a0l, bhv, acc[0][nt]);
            acc[0][nt] = mfma16(a0h, blv, acc[0][nt]);
            acc[1][nt] = mfma16(a1h, bhv, acc[1][nt]);
            acc[1][nt] = mfma16(a1l, bhv, acc[1][nt]);
            acc[1][nt] = mfma16(a1h, blv, acc[1][nt]);
        }
    }

    const int nbase = wave * 256;
#pragma unroll
    for (int nt = 0; nt < 16; ++nt) {
        const int col = nbase + nt * 16 + l15;
        const float bvl = bd[col];
#pragma unroll
        for (int mt = 0; mt < 2; ++mt)
#pragma unroll
            for (int i = 0; i < 4; ++i)
                C[(r0 + mt * 16 + quad * 4 + i) * D_DIM + col] =
                    acc[mt][nt][i] + bvl;
    }
}

// ---------------------------------------------------------------------------
extern "C" void kernel_launch(void* const* d_in, const int* in_sizes, int n_in,
                              void* d_out, int out_size, void* d_ws, size_t ws_size,
                              hipStream_t stream) {
    (void)in_sizes; (void)n_in; (void)out_size; (void)ws_size;
    const int*   y     = (const int*)  d_in[0];
    const float* embed = (const float*)d_in[1];
    const float* Wx    = (const float*)d_in[2];
    const float* Wh    = (const float*)d_in[3];
    const float* bx    = (const float*)d_in[4];
    const float* bh    = (const float*)d_in[5];
    const float* Wd    = (const float*)d_in[6];
    const float* bd    = (const float*)d_in[7];
    const float* h0    = (const float*)d_in[8];
    float* out = (float*)d_out;

    // workspace: WdT hi/lo (2+2 MB) + flags (8 KB)
    bf16* WdTh = (bf16*)d_ws;
    bf16* WdTl = WdTh + (size_t)D_DIM * D_DIM;
    int* flags = (int*)((char*)d_ws + (size_t)D_DIM * D_DIM * 4);

    hipMemsetAsync(flags, 0, 8192, stream);

    transpose_split<<<dim3(D_DIM / 32, D_DIM / 32), dim3(32, 8), 0, stream>>>(
        Wd, WdTh, WdTl, D_DIM, D_DIM);

    // GRU scan with fused input projections; packed h history -> d_out rows
    gru_scan<<<128, 256, 0, stream>>>(Wx, Wh, bx, bh, h0, embed, y,
                                      (uint32_t*)out, flags);

    // In-place: out rows = h rows @ Wd + bd
    gemm_rows_inplace<<<M_REAL / 32, 256, 0, stream>>>(out, WdTh, WdTl, bd);
}

// Round 7
// 7192.689 us; speedup vs baseline: 1.2592x; 1.0173x over previous
//
#include <hip/hip_runtime.h>
#include <hip/hip_bf16.h>
#include <cstdint>

typedef __bf16 bf16;
typedef __bf16 bf16x8 __attribute__((ext_vector_type(8)));
typedef float  f32x4  __attribute__((ext_vector_type(4)));
typedef uint32_t u32x4 __attribute__((ext_vector_type(4)));

#define D_DIM   1024
#define ND      3072
#define B_SZ    32
#define U_SZ    512
#define T_SZ    513
#define M_REAL  (B_SZ * T_SZ)   // 16416
#define WXS_LD  1032            // padded k-stride

#define AGENT __HIP_MEMORY_SCOPE_AGENT

__device__ __forceinline__ f32x4 mfma16(bf16x8 a, bf16x8 b, f32x4 c) {
    return __builtin_amdgcn_mfma_f32_16x16x32_bf16(a, b, c, 0, 0, 0);
}

struct bfpair { bf16x8 hi, lo; };

// split 8 consecutive fp32 into bf16 hi + bf16 residual lo
__device__ __forceinline__ bfpair split8(const float* p) {
    f32x4 a = *(const f32x4*)p;
    f32x4 b = *(const f32x4*)(p + 4);
    bfpair r;
#pragma unroll
    for (int j = 0; j < 4; ++j) {
        r.hi[j] = (bf16)a[j];
        r.lo[j] = (bf16)(a[j] - (float)r.hi[j]);
        r.hi[4 + j] = (bf16)b[j];
        r.lo[4 + j] = (bf16)(b[j] - (float)r.hi[4 + j]);
    }
    return r;
}

// convert 8 consecutive fp32 to bf16
__device__ __forceinline__ bf16x8 cvt8(const float* p) {
    f32x4 a = *(const f32x4*)p;
    f32x4 b = *(const f32x4*)(p + 4);
    bf16x8 r;
#pragma unroll
    for (int j = 0; j < 4; ++j) { r[j] = (bf16)a[j]; r[4 + j] = (bf16)b[j]; }
    return r;
}

// unpack 8 packed uint32 (hi bf16 | lo bf16 << 16) -> hi8, lo8 via v_perm
__device__ __forceinline__ bfpair unpack8(const uint32_t* p) {
    u32x4 a = *(const u32x4*)p;
    u32x4 b = *(const u32x4*)(p + 4);
    union { uint32_t u[4]; bf16x8 v; } H, L;
    H.u[0] = __builtin_amdgcn_perm(a.y, a.x, 0x05040100u);
    H.u[1] = __builtin_amdgcn_perm(a.w, a.z, 0x05040100u);
    H.u[2] = __builtin_amdgcn_perm(b.y, b.x, 0x05040100u);
    H.u[3] = __builtin_amdgcn_perm(b.w, b.z, 0x05040100u);
    L.u[0] = __builtin_amdgcn_perm(a.y, a.x, 0x07060302u);
    L.u[1] = __builtin_amdgcn_perm(a.w, a.z, 0x07060302u);
    L.u[2] = __builtin_amdgcn_perm(b.y, b.x, 0x07060302u);
    L.u[3] = __builtin_amdgcn_perm(b.w, b.z, 0x07060302u);
    bfpair r; r.hi = H.v; r.lo = L.v;
    return r;
}

// ---------------------------------------------------------------------------
// Transpose fp32 Wd [K][N] -> bf16 hi/lo planes in MFMA-FRAGMENT ORDER (R12):
//   for each (16-col group cg, 32-k slice ks) the 64 lanes' bf16x8 fragments
//   are contiguous (1 KB per plane) -> every B-frag load in the GEMM is a
//   fully coalesced wave read.
// ---------------------------------------------------------------------------
__global__ void transpose_split(const float* __restrict__ in,
                                bf16* __restrict__ out_hi, bf16* __restrict__ out_lo,
                                int R, int C) {
    __shared__ float tile[32][33];
    const int c0 = blockIdx.x * 32, r0 = blockIdx.y * 32;
    const int tx = threadIdx.x, ty = threadIdx.y;   // 32 x 8
    for (int i = 0; i < 32; i += 8)
        tile[ty + i][tx] = in[(size_t)(r0 + ty + i) * C + c0 + tx];
    __syncthreads();
    for (int i = 0; i < 32; i += 8) {
        const float v  = tile[tx][ty + i];
        const bf16  hi = (bf16)v;
        const int col = c0 + ty + i;      // output col (N)
        const int row = r0 + tx;          // output row (K)
        const size_t idx = ((size_t)((col >> 4) * 32 + (row >> 5)) << 9)
                         + (((row >> 3) & 3) << 7) + ((col & 15) << 3) + (row & 7);
        out_hi[idx] = hi;
        out_lo[idx] = (bf16)(v - (float)hi);
    }
}

// ---------------------------------------------------------------------------
// GRU scan — R6 structure byte-identical (measured best: ~6850-6885 us).
//   128 persistent WGs x 256 threads; block = (mhalf, 16-dim slice).
//   Zero-RMW two-hop barrier: arrive = relaxed store to per-block slot;
//   block 0 wave 0 sweeps all 128 slots in parallel, then stores go=t+1
//   replicated on 8 lines; others spin on their go line.
//   (R7-R11 structural variants all regressed. Do not touch.)
// ---------------------------------------------------------------------------
__global__ __launch_bounds__(256, 1)
void gru_scan(const float* __restrict__ Wx,    const float* __restrict__ Wh,
              const float* __restrict__ bx,    const float* __restrict__ bh,
              const float* __restrict__ h0,    const float* __restrict__ embed,
              const int* __restrict__ y,       uint32_t* __restrict__ ghs,
              int* __restrict__ flags)
{
    __shared__ __align__(16) bf16 WxS[48 * WXS_LD];  // [c = gate*16+cl][k]
    __shared__ float hpx[48 * 17];
    __shared__ float xpx[2][48 * 17];
    __shared__ float bhs[48], bxs[48];

    const int tid  = threadIdx.x;
    const int wave = tid >> 6, lane = tid & 63;
    const int quad = lane >> 4, l15 = lane & 15;
    const int mhalf = blockIdx.x & 1;
    const int n0 = (blockIdx.x >> 1) * 16;
    int* slots = flags;          // slot for block b at flags[b*4]  (16-B stride)
    int* go    = flags + 512;    // go line j at flags[512 + j*16], j=0..7

    // ---- one-time: gather Wx slice [48 cols][1024 k] from fp32 Wx[k][3D] ----
    for (int idx = tid; idx < 3 * 1024 * 16; idx += 256) {
        const int cl = idx & 15;
        const int k  = (idx >> 4) & 1023;
        const int g  = idx >> 14;            // 0..2
        WxS[(g * 16 + cl) * WXS_LD + k] = (bf16)Wx[(size_t)k * ND + g * D_DIM + n0 + cl];
    }
    if (tid < 48) {
        bhs[tid] = bh[(tid >> 4) * D_DIM + n0 + (tid & 15)];
        bxs[tid] = bx[(tid >> 4) * D_DIM + n0 + (tid & 15)];
    }

    // ---- one-time: gather Wh gate-slice into registers (waves 0..2) ----
    bf16x8 breg[32];
    if (wave < 3) {
#pragma unroll
        for (int ks = 0; ks < 32; ++ks) {
            bf16x8 v;
#pragma unroll
            for (int j = 0; j < 8; ++j)
                v[j] = (bf16)Wh[(size_t)(ks * 32 + quad * 8 + j) * ND
                                + wave * D_DIM + n0 + l15];
            breg[ks] = v;
        }
    }

    // gate-phase identity: one (batch, dim) output per thread
    const int gml = tid >> 4, nl = tid & 15;
    const int gb  = mhalf * 16 + gml;
    const int gn  = n0 + nl;
    float hold = h0[gn];
    uint32_t pkjunk = 0;

    __syncthreads();

    // ---- pre-loop: xp(0), all tokens NULL (embed row 0) -> xpx[0] ----
    if (wave == 3) {
        const float* xrow = embed + quad * 8;
        f32x4 ax0 = {}, ax1 = {}, ax2 = {};
#pragma unroll
        for (int ks = 0; ks < 32; ++ks) {
            bf16x8 xa = cvt8(xrow + ks * 32);
            bf16x8 w0 = *(const bf16x8*)(WxS + (l15)      * WXS_LD + ks * 32 + quad * 8);
            bf16x8 w1 = *(const bf16x8*)(WxS + (16 + l15) * WXS_LD + ks * 32 + quad * 8);
            bf16x8 w2 = *(const bf16x8*)(WxS + (32 + l15) * WXS_LD + ks * 32 + quad * 8);
            ax0 = mfma16(xa, w0, ax0);
            ax1 = mfma16(xa, w1, ax1);
            ax2 = mfma16(xa, w2, ax2);
        }
#pragma unroll
        for (int i = 0; i < 4; ++i) {
            xpx[0][(quad * 4 + i) * 17 + l15]      = ax0[i];
            xpx[0][(16 + quad * 4 + i) * 17 + l15] = ax1[i];
            xpx[0][(32 + quad * 4 + i) * 17 + l15] = ax2[i];
        }
    }

    for (int t = 0; t < T_SZ; ++t) {
        // ---- waves 0..2: hp = h_{t-1} @ Wh slice, split-precision A ----
        if (wave < 3) {
            f32x4 a0 = {}, a1 = {};
            if (t == 0) {
                const float* hrow = h0 + quad * 8;
#pragma unroll
                for (int ks = 0; ks < 32; ++ks) {
                    bfpair h8 = split8(hrow + ks * 32);
                    a0 = mfma16(h8.hi, breg[ks], a0);
                    a1 = mfma16(h8.lo, breg[ks], a1);
                }
            } else {
                const uint32_t* hrow = ghs
                    + ((size_t)(mhalf * 16 + l15) * T_SZ + (t - 1)) * D_DIM + quad * 8;
#pragma unroll
                for (int ks = 0; ks < 32; ++ks) {
                    bfpair h8 = unpack8(hrow + ks * 32);
                    a0 = mfma16(h8.hi, breg[ks], a0);
                    a1 = mfma16(h8.lo, breg[ks], a1);
                }
            }
            a0 = a0 + a1;
#pragma unroll
            for (int i = 0; i < 4; ++i)
                hpx[(wave * 16 + quad * 4 + i) * 17 + l15] = a0[i];
        }

        // ---- wave 3: xp(t+1), off critical path ----
        if (wave == 3 && t < U_SZ) {
            const int tok = y[(mhalf * 16 + l15) * U_SZ + t] & 1023;  // token at step t+1
            const float* xrow = embed + (size_t)tok * D_DIM + quad * 8;
            const int p = (t + 1) & 1;
            f32x4 ax0 = {}, ax1 = {}, ax2 = {};
#pragma unroll
            for (int ks = 0; ks < 32; ++ks) {
                bf16x8 xa = cvt8(xrow + ks * 32);
                bf16x8 w0 = *(const bf16x8*)(WxS + (l15)      * WXS_LD + ks * 32 + quad * 8);
                bf16x8 w1 = *(const bf16x8*)(WxS + (16 + l15) * WXS_LD + ks * 32 + quad * 8);
                bf16x8 w2 = *(const bf16x8*)(WxS + (32 + l15) * WXS_LD + ks * 32 + quad * 8);
                ax0 = mfma16(xa, w0, ax0);
                ax1 = mfma16(xa, w1, ax1);
                ax2 = mfma16(xa, w2, ax2);
            }
#pragma unroll
            for (int i = 0; i < 4; ++i) {
                xpx[p][(quad * 4 + i) * 17 + l15]      = ax0[i];
                xpx[p][(16 + quad * 4 + i) * 17 + l15] = ax1[i];
                xpx[p][(32 + quad * 4 + i) * 17 + l15] = ax2[i];
            }
        }
        __syncthreads();

        // ---- gates: one (gb, gn) per thread; publish packed hi/lo h ----
        {
            const int p = t & 1;
            const float xz = xpx[p][(gml)      * 17 + nl] + bxs[nl];
            const float xr = xpx[p][(16 + gml) * 17 + nl] + bxs[16 + nl];
            const float xh = xpx[p][(32 + gml) * 17 + nl] + bxs[32 + nl];
            const float hz = hpx[(gml)      * 17 + nl] + bhs[nl];
            const float hr = hpx[(16 + gml) * 17 + nl] + bhs[16 + nl];
            const float hh = hpx[(32 + gml) * 17 + nl] + bhs[32 + nl];
            const float z  = 1.f / (1.f + __expf(-(xz + hz)));
            const float r  = 1.f / (1.f + __expf(-(xr + hr)));
            const float pa = xh + r * hh;
            const float hc = 1.f - 2.f / (__expf(2.f * pa) + 1.f);   // tanh(pa)
            const float hn = z * hold + (1.f - z) * hc;
            hold = hn;
            union { uint16_t u[2]; uint32_t w; } pk;
            const bf16 hi = (bf16)hn;
            const bf16 lo = (bf16)(hn - (float)hi);
            pk.u[0] = __builtin_bit_cast(uint16_t, hi);
            pk.u[1] = __builtin_bit_cast(uint16_t, lo);
            uint32_t old = __hip_atomic_exchange(
                ghs + ((size_t)gb * T_SZ + t) * D_DIM + gn, pk.w,
                __ATOMIC_RELAXED, AGENT);
            pkjunk ^= old;
        }

        // ---- zero-RMW device barrier: publish h_t ----
        if (t + 1 < T_SZ) {
            __syncthreads();   // s_waitcnt vmcnt(0) first: drains exchanges
            const int tv = t + 1;
            if (blockIdx.x == 0) {
                if (wave == 0) {
                    // parallel sweep: lane covers slots {lane, lane+64};
                    // slot 0 is ourselves (arrived by construction)
                    int ok;
                    do {
                        const int s1 = __hip_atomic_load(slots + lane * 4,
                                                         __ATOMIC_RELAXED, AGENT);
                        const int s2 = __hip_atomic_load(slots + (lane + 64) * 4,
                                                         __ATOMIC_RELAXED, AGENT);
                        ok = (lane == 0 || s1 >= tv) && (s2 >= tv);
                    } while (!__all(ok));
                    if (lane < 8)
                        __hip_atomic_store(go + lane * 16, tv,
                                           __ATOMIC_RELAXED, AGENT);
                }
            } else {
                if (tid == 0) {
                    __hip_atomic_store(slots + blockIdx.x * 4, tv,
                                       __ATOMIC_RELAXED, AGENT);
                    while (__hip_atomic_load(go + (blockIdx.x & 7) * 16,
                                             __ATOMIC_RELAXED, AGENT) < tv) {}
                }
            }
            __syncthreads();
        }
    }

    // consume pkjunk so the exchanges keep their returning form
    if (pkjunk == 0xDEADBEEFu) flags[1023] = 1;
}

// ---------------------------------------------------------------------------
// In-place row-block GEMM (R13): M_tile=64, zero LDS, 512 threads / 8 waves.
//   Each wave owns 128 output cols (8 col-groups) x all 64 rows.
//   A fragments are loaded DIRECTLY from global per wave (scan's unpack8
//   pattern); the 8 waves' redundant A reads hit L1 (8 KB slice per ks).
//   B traffic halves vs 32-row tiles: 257 blocks x 4 MB = 1.03 GB.
//   One __syncthreads between MFMA loop and stores makes in-place safe.
//   Partial last chunk: clamped A-row reads + guarded stores.
// ---------------------------------------------------------------------------
__global__ __launch_bounds__(512, 1)
void gemm_rows_inplace(float* __restrict__ C,
                       const bf16* __restrict__ WdTh, const bf16* __restrict__ WdTl,
                       const float* __restrict__ bd)
{
    const int tid  = threadIdx.x;
    const int wave = tid >> 6, lane = tid & 63;
    const int quad = lane >> 4, l15 = lane & 15;
    const size_t r0 = (size_t)blockIdx.x * 64;
    const uint32_t* Cw = (const uint32_t*)C;

    // A-row per mt group for this lane, clamped for the partial last chunk
    int rows[4];
#pragma unroll
    for (int mt = 0; mt < 4; ++mt) {
        int r = (int)r0 + mt * 16 + l15;
        rows[mt] = (r < M_REAL) ? r : (M_REAL - 1);
    }

    f32x4 acc[4][8] = {};
    for (int ks = 0; ks < 32; ++ks) {
        bfpair a0 = unpack8(Cw + (size_t)rows[0] * D_DIM + ks * 32 + quad * 8);
        bfpair a1 = unpack8(Cw + (size_t)rows[1] * D_DIM + ks * 32 + quad * 8);
        bfpair a2 = unpack8(Cw + (size_t)rows[2] * D_DIM + ks * 32 + quad * 8);
        bfpair a3 = unpack8(Cw + (size_t)rows[3] * D_DIM + ks * 32 + quad * 8);
#pragma unroll
        for (int nt = 0; nt < 8; ++nt) {
            const int cg = wave * 8 + nt;      // 16-col group 0..63
            const size_t boff = (((size_t)cg * 32 + ks) << 9) + (size_t)lane * 8;
            bf16x8 bhv = *(const bf16x8*)(WdTh + boff);
            bf16x8 blv = *(const bf16x8*)(WdTl + boff);
            acc[0][nt] = mfma16(a0.hi, bhv, acc[0][nt]);
            acc[0][nt] = mfma16(a0.lo, bhv, acc[0][nt]);
            acc[0][nt] = mfma16(a0.hi, blv, acc[0][nt]);
            acc[1][nt] = mfma16(a1.hi, bhv, acc[1][nt]);
            acc[1][nt] = mfma16(a1.lo, bhv, acc[1][nt]);
            acc[1][nt] = mfma16(a1.hi, blv, acc[1][nt]);
            acc[2][nt] = mfma16(a2.hi, bhv, acc[2][nt]);
            acc[2][nt] = mfma16(a2.lo, bhv, acc[2][nt]);
            acc[2][nt] = mfma16(a2.hi, blv, acc[2][nt]);
            acc[3][nt] = mfma16(a3.hi, bhv, acc[3][nt]);
            acc[3][nt] = mfma16(a3.lo, bhv, acc[3][nt]);
            acc[3][nt] = mfma16(a3.hi, blv, acc[3][nt]);
        }
    }

    __syncthreads();   // all waves' A reads complete before any in-place store

#pragma unroll
    for (int nt = 0; nt < 8; ++nt) {
        const int col = wave * 128 + nt * 16 + l15;
        const float bvl = bd[col];
#pragma unroll
        for (int mt = 0; mt < 4; ++mt) {
#pragma unroll
            for (int i = 0; i < 4; ++i) {
                const size_t row = r0 + mt * 16 + quad * 4 + i;
                if (row < M_REAL)
                    C[row * D_DIM + col] = acc[mt][nt][i] + bvl;
            }
        }
    }
}

// ---------------------------------------------------------------------------
extern "C" void kernel_launch(void* const* d_in, const int* in_sizes, int n_in,
                              void* d_out, int out_size, void* d_ws, size_t ws_size,
                              hipStream_t stream) {
    (void)in_sizes; (void)n_in; (void)out_size; (void)ws_size;
    const int*   y     = (const int*)  d_in[0];
    const float* embed = (const float*)d_in[1];
    const float* Wx    = (const float*)d_in[2];
    const float* Wh    = (const float*)d_in[3];
    const float* bx    = (const float*)d_in[4];
    const float* bh    = (const float*)d_in[5];
    const float* Wd    = (const float*)d_in[6];
    const float* bd    = (const float*)d_in[7];
    const float* h0    = (const float*)d_in[8];
    float* out = (float*)d_out;

    // workspace: WdT hi/lo (2+2 MB) + flags (8 KB)
    bf16* WdTh = (bf16*)d_ws;
    bf16* WdTl = WdTh + (size_t)D_DIM * D_DIM;
    int* flags = (int*)((char*)d_ws + (size_t)D_DIM * D_DIM * 4);

    hipMemsetAsync(flags, 0, 8192, stream);

    transpose_split<<<dim3(D_DIM / 32, D_DIM / 32), dim3(32, 8), 0, stream>>>(
        Wd, WdTh, WdTl, D_DIM, D_DIM);

    // GRU scan with fused input projections; packed h history -> d_out rows
    gru_scan<<<128, 256, 0, stream>>>(Wx, Wh, bx, bh, h0, embed, y,
                                      (uint32_t*)out, flags);

    // In-place: out rows = h rows @ Wd + bd  (64-row tiles, zero LDS)
    gemm_rows_inplace<<<(M_REAL + 63) / 64, 512, 0, stream>>>(out, WdTh, WdTl, bd);
}

// Round 8
// 7187.594 us; speedup vs baseline: 1.2601x; 1.0007x over previous
//
#include <hip/hip_runtime.h>
#include <hip/hip_bf16.h>
#include <cstdint>

typedef __bf16 bf16;
typedef __bf16 bf16x8 __attribute__((ext_vector_type(8)));
typedef float  f32x4  __attribute__((ext_vector_type(4)));
typedef uint32_t u32x4 __attribute__((ext_vector_type(4)));

#define D_DIM   1024
#define ND      3072
#define B_SZ    32
#define U_SZ    512
#define T_SZ    513
#define M_REAL  (B_SZ * T_SZ)   // 16416
#define WXS_LD  1032            // padded k-stride

#define AGENT __HIP_MEMORY_SCOPE_AGENT

__device__ __forceinline__ f32x4 mfma16(bf16x8 a, bf16x8 b, f32x4 c) {
    return __builtin_amdgcn_mfma_f32_16x16x32_bf16(a, b, c, 0, 0, 0);
}

struct bfpair { bf16x8 hi, lo; };

// split 8 consecutive fp32 into bf16 hi + bf16 residual lo
__device__ __forceinline__ bfpair split8(const float* p) {
    f32x4 a = *(const f32x4*)p;
    f32x4 b = *(const f32x4*)(p + 4);
    bfpair r;
#pragma unroll
    for (int j = 0; j < 4; ++j) {
        r.hi[j] = (bf16)a[j];
        r.lo[j] = (bf16)(a[j] - (float)r.hi[j]);
        r.hi[4 + j] = (bf16)b[j];
        r.lo[4 + j] = (bf16)(b[j] - (float)r.hi[4 + j]);
    }
    return r;
}

// convert 8 consecutive fp32 to bf16
__device__ __forceinline__ bf16x8 cvt8(const float* p) {
    f32x4 a = *(const f32x4*)p;
    f32x4 b = *(const f32x4*)(p + 4);
    bf16x8 r;
#pragma unroll
    for (int j = 0; j < 4; ++j) { r[j] = (bf16)a[j]; r[4 + j] = (bf16)b[j]; }
    return r;
}

// unpack 8 packed uint32 (hi bf16 | lo bf16 << 16) -> hi8, lo8 via v_perm
__device__ __forceinline__ bfpair unpack8(const uint32_t* p) {
    u32x4 a = *(const u32x4*)p;
    u32x4 b = *(const u32x4*)(p + 4);
    union { uint32_t u[4]; bf16x8 v; } H, L;
    H.u[0] = __builtin_amdgcn_perm(a.y, a.x, 0x05040100u);
    H.u[1] = __builtin_amdgcn_perm(a.w, a.z, 0x05040100u);
    H.u[2] = __builtin_amdgcn_perm(b.y, b.x, 0x05040100u);
    H.u[3] = __builtin_amdgcn_perm(b.w, b.z, 0x05040100u);
    L.u[0] = __builtin_amdgcn_perm(a.y, a.x, 0x07060302u);
    L.u[1] = __builtin_amdgcn_perm(a.w, a.z, 0x07060302u);
    L.u[2] = __builtin_amdgcn_perm(b.y, b.x, 0x07060302u);
    L.u[3] = __builtin_amdgcn_perm(b.w, b.z, 0x07060302u);
    bfpair r; r.hi = H.v; r.lo = L.v;
    return r;
}

// ---------------------------------------------------------------------------
// Transpose fp32 Wd [K][N] -> bf16 hi/lo planes in MFMA-FRAGMENT ORDER (R12):
//   for each (16-col group cg, 32-k slice ks) the 64 lanes' bf16x8 fragments
//   are contiguous (1 KB per plane) -> every B-frag load in the GEMM is a
//   fully coalesced wave read.
// ---------------------------------------------------------------------------
__global__ void transpose_split(const float* __restrict__ in,
                                bf16* __restrict__ out_hi, bf16* __restrict__ out_lo,
                                int R, int C) {
    __shared__ float tile[32][33];
    const int c0 = blockIdx.x * 32, r0 = blockIdx.y * 32;
    const int tx = threadIdx.x, ty = threadIdx.y;   // 32 x 8
    for (int i = 0; i < 32; i += 8)
        tile[ty + i][tx] = in[(size_t)(r0 + ty + i) * C + c0 + tx];
    __syncthreads();
    for (int i = 0; i < 32; i += 8) {
        const float v  = tile[tx][ty + i];
        const bf16  hi = (bf16)v;
        const int col = c0 + ty + i;      // output col (N)
        const int row = r0 + tx;          // output row (K)
        const size_t idx = ((size_t)((col >> 4) * 32 + (row >> 5)) << 9)
                         + (((row >> 3) & 3) << 7) + ((col & 15) << 3) + (row & 7);
        out_hi[idx] = hi;
        out_lo[idx] = (bf16)(v - (float)hi);
    }
}

// ---------------------------------------------------------------------------
// GRU scan (R14) = R6 compute structure verbatim + SPLIT device barrier.
//   Key observation: block (mhalf, n0) only exchanges h data with blocks of
//   the SAME mhalf (reads/writes rows mhalf*16..mhalf*16+15 only). The two
//   mhalf groups are fully independent 64-block scan chains, so each gets
//   its own barrier: group g slots at flags[g*256 + j*4] (j = blockIdx>>1),
//   go lines at flags[512 + g*256 + i*16], leader = block g. Effects:
//   last-arrival over 64 not 128 blocks, 1-load/lane sweep, and the groups
//   drift apart so their MALL bursts de-synchronize.
//   (R7-R11 compute restructures all regressed. Compute untouched.)
// ---------------------------------------------------------------------------
__global__ __launch_bounds__(256, 1)
void gru_scan(const float* __restrict__ Wx,    const float* __restrict__ Wh,
              const float* __restrict__ bx,    const float* __restrict__ bh,
              const float* __restrict__ h0,    const float* __restrict__ embed,
              const int* __restrict__ y,       uint32_t* __restrict__ ghs,
              int* __restrict__ flags)
{
    __shared__ __align__(16) bf16 WxS[48 * WXS_LD];  // [c = gate*16+cl][k]
    __shared__ float hpx[48 * 17];
    __shared__ float xpx[2][48 * 17];
    __shared__ float bhs[48], bxs[48];

    const int tid  = threadIdx.x;
    const int wave = tid >> 6, lane = tid & 63;
    const int quad = lane >> 4, l15 = lane & 15;
    const int mhalf = blockIdx.x & 1;
    const int n0 = (blockIdx.x >> 1) * 16;
    // per-group barrier state (group = mhalf)
    int* gslots = flags + mhalf * 256;        // 64 slots, 16-B stride
    int* ggo    = flags + 512 + mhalf * 256;  // 8 go lines, 64-B stride
    const int sidx = blockIdx.x >> 1;         // slot index within group

    // ---- one-time: gather Wx slice [48 cols][1024 k] from fp32 Wx[k][3D] ----
    for (int idx = tid; idx < 3 * 1024 * 16; idx += 256) {
        const int cl = idx & 15;
        const int k  = (idx >> 4) & 1023;
        const int g  = idx >> 14;            // 0..2
        WxS[(g * 16 + cl) * WXS_LD + k] = (bf16)Wx[(size_t)k * ND + g * D_DIM + n0 + cl];
    }
    if (tid < 48) {
        bhs[tid] = bh[(tid >> 4) * D_DIM + n0 + (tid & 15)];
        bxs[tid] = bx[(tid >> 4) * D_DIM + n0 + (tid & 15)];
    }

    // ---- one-time: gather Wh gate-slice into registers (waves 0..2) ----
    bf16x8 breg[32];
    if (wave < 3) {
#pragma unroll
        for (int ks = 0; ks < 32; ++ks) {
            bf16x8 v;
#pragma unroll
            for (int j = 0; j < 8; ++j)
                v[j] = (bf16)Wh[(size_t)(ks * 32 + quad * 8 + j) * ND
                                + wave * D_DIM + n0 + l15];
            breg[ks] = v;
        }
    }

    // gate-phase identity: one (batch, dim) output per thread
    const int gml = tid >> 4, nl = tid & 15;
    const int gb  = mhalf * 16 + gml;
    const int gn  = n0 + nl;
    float hold = h0[gn];
    uint32_t pkjunk = 0;

    __syncthreads();

    // ---- pre-loop: xp(0), all tokens NULL (embed row 0) -> xpx[0] ----
    if (wave == 3) {
        const float* xrow = embed + quad * 8;
        f32x4 ax0 = {}, ax1 = {}, ax2 = {};
#pragma unroll
        for (int ks = 0; ks < 32; ++ks) {
            bf16x8 xa = cvt8(xrow + ks * 32);
            bf16x8 w0 = *(const bf16x8*)(WxS + (l15)      * WXS_LD + ks * 32 + quad * 8);
            bf16x8 w1 = *(const bf16x8*)(WxS + (16 + l15) * WXS_LD + ks * 32 + quad * 8);
            bf16x8 w2 = *(const bf16x8*)(WxS + (32 + l15) * WXS_LD + ks * 32 + quad * 8);
            ax0 = mfma16(xa, w0, ax0);
            ax1 = mfma16(xa, w1, ax1);
            ax2 = mfma16(xa, w2, ax2);
        }
#pragma unroll
        for (int i = 0; i < 4; ++i) {
            xpx[0][(quad * 4 + i) * 17 + l15]      = ax0[i];
            xpx[0][(16 + quad * 4 + i) * 17 + l15] = ax1[i];
            xpx[0][(32 + quad * 4 + i) * 17 + l15] = ax2[i];
        }
    }

    for (int t = 0; t < T_SZ; ++t) {
        // ---- waves 0..2: hp = h_{t-1} @ Wh slice, split-precision A ----
        if (wave < 3) {
            f32x4 a0 = {}, a1 = {};
            if (t == 0) {
                const float* hrow = h0 + quad * 8;
#pragma unroll
                for (int ks = 0; ks < 32; ++ks) {
                    bfpair h8 = split8(hrow + ks * 32);
                    a0 = mfma16(h8.hi, breg[ks], a0);
                    a1 = mfma16(h8.lo, breg[ks], a1);
                }
            } else {
                const uint32_t* hrow = ghs
                    + ((size_t)(mhalf * 16 + l15) * T_SZ + (t - 1)) * D_DIM + quad * 8;
#pragma unroll
                for (int ks = 0; ks < 32; ++ks) {
                    bfpair h8 = unpack8(hrow + ks * 32);
                    a0 = mfma16(h8.hi, breg[ks], a0);
                    a1 = mfma16(h8.lo, breg[ks], a1);
                }
            }
            a0 = a0 + a1;
#pragma unroll
            for (int i = 0; i < 4; ++i)
                hpx[(wave * 16 + quad * 4 + i) * 17 + l15] = a0[i];
        }

        // ---- wave 3: xp(t+1), off critical path ----
        if (wave == 3 && t < U_SZ) {
            const int tok = y[(mhalf * 16 + l15) * U_SZ + t] & 1023;  // token at step t+1
            const float* xrow = embed + (size_t)tok * D_DIM + quad * 8;
            const int p = (t + 1) & 1;
            f32x4 ax0 = {}, ax1 = {}, ax2 = {};
#pragma unroll
            for (int ks = 0; ks < 32; ++ks) {
                bf16x8 xa = cvt8(xrow + ks * 32);
                bf16x8 w0 = *(const bf16x8*)(WxS + (l15)      * WXS_LD + ks * 32 + quad * 8);
                bf16x8 w1 = *(const bf16x8*)(WxS + (16 + l15) * WXS_LD + ks * 32 + quad * 8);
                bf16x8 w2 = *(const bf16x8*)(WxS + (32 + l15) * WXS_LD + ks * 32 + quad * 8);
                ax0 = mfma16(xa, w0, ax0);
                ax1 = mfma16(xa, w1, ax1);
                ax2 = mfma16(xa, w2, ax2);
            }
#pragma unroll
            for (int i = 0; i < 4; ++i) {
                xpx[p][(quad * 4 + i) * 17 + l15]      = ax0[i];
                xpx[p][(16 + quad * 4 + i) * 17 + l15] = ax1[i];
                xpx[p][(32 + quad * 4 + i) * 17 + l15] = ax2[i];
            }
        }
        __syncthreads();

        // ---- gates: one (gb, gn) per thread; publish packed hi/lo h ----
        {
            const int p = t & 1;
            const float xz = xpx[p][(gml)      * 17 + nl] + bxs[nl];
            const float xr = xpx[p][(16 + gml) * 17 + nl] + bxs[16 + nl];
            const float xh = xpx[p][(32 + gml) * 17 + nl] + bxs[32 + nl];
            const float hz = hpx[(gml)      * 17 + nl] + bhs[nl];
            const float hr = hpx[(16 + gml) * 17 + nl] + bhs[16 + nl];
            const float hh = hpx[(32 + gml) * 17 + nl] + bhs[32 + nl];
            const float z  = 1.f / (1.f + __expf(-(xz + hz)));
            const float r  = 1.f / (1.f + __expf(-(xr + hr)));
            const float pa = xh + r * hh;
            const float hc = 1.f - 2.f / (__expf(2.f * pa) + 1.f);   // tanh(pa)
            const float hn = z * hold + (1.f - z) * hc;
            hold = hn;
            union { uint16_t u[2]; uint32_t w; } pk;
            const bf16 hi = (bf16)hn;
            const bf16 lo = (bf16)(hn - (float)hi);
            pk.u[0] = __builtin_bit_cast(uint16_t, hi);
            pk.u[1] = __builtin_bit_cast(uint16_t, lo);
            uint32_t old = __hip_atomic_exchange(
                ghs + ((size_t)gb * T_SZ + t) * D_DIM + gn, pk.w,
                __ATOMIC_RELAXED, AGENT);
            pkjunk ^= old;
        }

        // ---- zero-RMW per-group (64-block) barrier: publish h_t ----
        if (t + 1 < T_SZ) {
            __syncthreads();   // s_waitcnt vmcnt(0) first: drains exchanges
            const int tv = t + 1;
            if (sidx == 0) {
                if (wave == 0) {
                    // parallel sweep: lane j covers slot j of this group;
                    // slot 0 is ourselves (arrived by construction)
                    int ok;
                    do {
                        const int s1 = __hip_atomic_load(gslots + lane * 4,
                                                         __ATOMIC_RELAXED, AGENT);
                        ok = (lane == 0) || (s1 >= tv);
                    } while (!__all(ok));
                    if (lane < 8)
                        __hip_atomic_store(ggo + lane * 16, tv,
                                           __ATOMIC_RELAXED, AGENT);
                }
            } else {
                if (tid == 0) {
                    __hip_atomic_store(gslots + sidx * 4, tv,
                                       __ATOMIC_RELAXED, AGENT);
                    while (__hip_atomic_load(ggo + (sidx & 7) * 16,
                                             __ATOMIC_RELAXED, AGENT) < tv) {}
                }
            }
            __syncthreads();
        }
    }

    // consume pkjunk so the exchanges keep their returning form
    if (pkjunk == 0xDEADBEEFu) flags[1023] = 1;
}

// ---------------------------------------------------------------------------
// In-place row-block GEMM (R13): M_tile=64, zero LDS, 512 threads / 8 waves.
//   Each wave owns 128 output cols (8 col-groups) x all 64 rows.
//   A fragments loaded directly from global per wave (unpack8 pattern);
//   the 8 waves' redundant A reads hit L1. B traffic: 257 blocks x 4 MB.
//   One __syncthreads between MFMA loop and stores makes in-place safe.
// ---------------------------------------------------------------------------
__global__ __launch_bounds__(512, 1)
void gemm_rows_inplace(float* __restrict__ C,
                       const bf16* __restrict__ WdTh, const bf16* __restrict__ WdTl,
                       const float* __restrict__ bd)
{
    const int tid  = threadIdx.x;
    const int wave = tid >> 6, lane = tid & 63;
    const int quad = lane >> 4, l15 = lane & 15;
    const size_t r0 = (size_t)blockIdx.x * 64;
    const uint32_t* Cw = (const uint32_t*)C;

    // A-row per mt group for this lane, clamped for the partial last chunk
    int rows[4];
#pragma unroll
    for (int mt = 0; mt < 4; ++mt) {
        int r = (int)r0 + mt * 16 + l15;
        rows[mt] = (r < M_REAL) ? r : (M_REAL - 1);
    }

    f32x4 acc[4][8] = {};
    for (int ks = 0; ks < 32; ++ks) {
        bfpair a0 = unpack8(Cw + (size_t)rows[0] * D_DIM + ks * 32 + quad * 8);
        bfpair a1 = unpack8(Cw + (size_t)rows[1] * D_DIM + ks * 32 + quad * 8);
        bfpair a2 = unpack8(Cw + (size_t)rows[2] * D_DIM + ks * 32 + quad * 8);
        bfpair a3 = unpack8(Cw + (size_t)rows[3] * D_DIM + ks * 32 + quad * 8);
#pragma unroll
        for (int nt = 0; nt < 8; ++nt) {
            const int cg = wave * 8 + nt;      // 16-col group 0..63
            const size_t boff = (((size_t)cg * 32 + ks) << 9) + (size_t)lane * 8;
            bf16x8 bhv = *(const bf16x8*)(WdTh + boff);
            bf16x8 blv = *(const bf16x8*)(WdTl + boff);
            acc[0][nt] = mfma16(a0.hi, bhv, acc[0][nt]);
            acc[0][nt] = mfma16(a0.lo, bhv, acc[0][nt]);
            acc[0][nt] = mfma16(a0.hi, blv, acc[0][nt]);
            acc[1][nt] = mfma16(a1.hi, bhv, acc[1][nt]);
            acc[1][nt] = mfma16(a1.lo, bhv, acc[1][nt]);
            acc[1][nt] = mfma16(a1.hi, blv, acc[1][nt]);
            acc[2][nt] = mfma16(a2.hi, bhv, acc[2][nt]);
            acc[2][nt] = mfma16(a2.lo, bhv, acc[2][nt]);
            acc[2][nt] = mfma16(a2.hi, blv, acc[2][nt]);
            acc[3][nt] = mfma16(a3.hi, bhv, acc[3][nt]);
            acc[3][nt] = mfma16(a3.lo, bhv, acc[3][nt]);
            acc[3][nt] = mfma16(a3.hi, blv, acc[3][nt]);
        }
    }

    __syncthreads();   // all waves' A reads complete before any in-place store

#pragma unroll
    for (int nt = 0; nt < 8; ++nt) {
        const int col = wave * 128 + nt * 16 + l15;
        const float bvl = bd[col];
#pragma unroll
        for (int mt = 0; mt < 4; ++mt) {
#pragma unroll
            for (int i = 0; i < 4; ++i) {
                const size_t row = r0 + mt * 16 + quad * 4 + i;
                if (row < M_REAL)
                    C[row * D_DIM + col] = acc[mt][nt][i] + bvl;
            }
        }
    }
}

// ---------------------------------------------------------------------------
extern "C" void kernel_launch(void* const* d_in, const int* in_sizes, int n_in,
                              void* d_out, int out_size, void* d_ws, size_t ws_size,
                              hipStream_t stream) {
    (void)in_sizes; (void)n_in; (void)out_size; (void)ws_size;
    const int*   y     = (const int*)  d_in[0];
    const float* embed = (const float*)d_in[1];
    const float* Wx    = (const float*)d_in[2];
    const float* Wh    = (const float*)d_in[3];
    const float* bx    = (const float*)d_in[4];
    const float* bh    = (const float*)d_in[5];
    const float* Wd    = (const float*)d_in[6];
    const float* bd    = (const float*)d_in[7];
    const float* h0    = (const float*)d_in[8];
    float* out = (float*)d_out;

    // workspace: WdT hi/lo (2+2 MB) + flags (8 KB)
    bf16* WdTh = (bf16*)d_ws;
    bf16* WdTl = WdTh + (size_t)D_DIM * D_DIM;
    int* flags = (int*)((char*)d_ws + (size_t)D_DIM * D_DIM * 4);

    hipMemsetAsync(flags, 0, 8192, stream);

    transpose_split<<<dim3(D_DIM / 32, D_DIM / 32), dim3(32, 8), 0, stream>>>(
        Wd, WdTh, WdTl, D_DIM, D_DIM);

    // GRU scan with fused input projections; packed h history -> d_out rows
    gru_scan<<<128, 256, 0, stream>>>(Wx, Wh, bx, bh, h0, embed, y,
                                      (uint32_t*)out, flags);

    // In-place: out rows = h rows @ Wd + bd  (64-row tiles, zero LDS)
    gemm_rows_inplace<<<(M_REAL + 63) / 64, 512, 0, stream>>>(out, WdTh, WdTl, bd);
}